// Round 8
// baseline (303.057 us; speedup 1.0000x reference)
//
#include <hip/hip_runtime.h>
#include <math.h>

// ---------------- constants from the reference ----------------
#define NCLS 10
#define TOPK 1000
#define DETS 100
#define CANDMAX 4096
#define SLOTS 16   // 16 * 64 lanes = 1024 >= TOPK (full fallback)
#define ACTK 256   // fast-path active set: 4 slots * 64 lanes

// score histogram: scores > 0.05 have (bits>>16) in [0x3D4C, 0x3F80) -> 564 bins
#define BIN0 0x3D4Cu
#define NBINS 576
#define NBLK 64    // blocks per image for the score/compact passes

__device__ __forceinline__ float sigmoidf_(float x) {
    return 1.0f / (1.0f + expf(-x));
}

__device__ __forceinline__ float key_score(const unsigned long long* key, int c) {
    return __uint_as_float(~(unsigned)(key[c] >> 32));
}

// K1: fused score + per-block LDS histogram (+ score cache) + last-block findP.
__global__ __launch_bounds__(256) void k_score_hist(const float* __restrict__ logits,
                                                    float* __restrict__ scores,
                                                    unsigned* hist,
                                                    unsigned* __restrict__ done,
                                                    unsigned* __restrict__ P,
                                                    int A, int use_scores) {
    __shared__ unsigned h[NBINS];
    __shared__ int s_last;
    int img = blockIdx.y;
    for (int i = threadIdx.x; i < NBINS; i += 256) h[i] = 0;
    __syncthreads();

    const float* base = logits + (size_t)img * A * NCLS;
    int nquad = A >> 2;
    for (int q = blockIdx.x * 256 + threadIdx.x; q < nquad; q += NBLK * 256) {
        const float4* lp = (const float4*)(base + (size_t)q * 40);
        float f[40];
#pragma unroll
        for (int i = 0; i < 10; ++i) ((float4*)f)[i] = lp[i];
        float4 s4;
        float* sv = &s4.x;
#pragma unroll
        for (int j = 0; j < 4; ++j) {
            float m = f[10 * j];
#pragma unroll
            for (int c = 1; c < 10; ++c) m = fmaxf(m, f[10 * j + c]);
            float sc = sigmoidf_(m);
            sc = (sc > 0.05f) ? sc : 0.0f;
            sv[j] = sc;
            if (sc > 0.0f) {
                unsigned bin = (__float_as_uint(sc) >> 16) - BIN0;
                if (bin >= NBINS) bin = NBINS - 1;
                atomicAdd(&h[bin], 1u);
            }
        }
        if (use_scores) ((float4*)(scores + (size_t)img * A))[q] = s4;
    }
    int tail0 = nquad << 2;
    if (blockIdx.x == 0) {
        for (int a = tail0 + (int)threadIdx.x; a < A; a += 256) {
            const float* lp2 = base + (size_t)a * NCLS;
            float m = lp2[0];
            for (int c = 1; c < 10; ++c) m = fmaxf(m, lp2[c]);
            float sc = sigmoidf_(m);
            sc = (sc > 0.05f) ? sc : 0.0f;
            if (use_scores) scores[(size_t)img * A + a] = sc;
            if (sc > 0.0f) {
                unsigned bin = (__float_as_uint(sc) >> 16) - BIN0;
                if (bin >= NBINS) bin = NBINS - 1;
                atomicAdd(&h[bin], 1u);
            }
        }
    }
    __syncthreads();
    for (int i = threadIdx.x; i < NBINS; i += 256) {
        unsigned c = h[i];
        if (c) atomicAdd(&hist[(size_t)img * NBINS + i], c);
    }
    __syncthreads();
    if (threadIdx.x == 0) {
        __threadfence();   // hist atomics ordered before done increment
        unsigned old = atomicAdd(&done[img], 1u);
        s_last = (old == (unsigned)(NBLK - 1)) ? 1 : 0;
    }
    __syncthreads();
    // last finishing block computes P (device-coherent atomic reads of hist)
    if (s_last && threadIdx.x < 64) {
        int lane = threadIdx.x;
        unsigned* hh = hist + (size_t)img * NBINS;
        unsigned b[9];
        unsigned s = 0;
#pragma unroll
        for (int j = 0; j < 9; ++j) { b[j] = atomicAdd(&hh[lane * 9 + j], 0u); s += b[j]; }
        unsigned suf = s;
#pragma unroll
        for (int d = 1; d < 64; d <<= 1) {
            unsigned o = __shfl_down(suf, d);
            if (lane + d < 64) suf += o;
        }
        unsigned above = __shfl_down(suf, 1);
        if (lane == 63) above = 0;
        if (lane == 0 && suf < (unsigned)TOPK) P[img] = 0u;
        if (above < (unsigned)TOPK && suf >= (unsigned)TOPK) {
            unsigned cum = above;
            for (int j = 8; j >= 0; --j) {
                cum += b[j];
                if (cum >= (unsigned)TOPK) { P[img] = BIN0 + (unsigned)(lane * 9 + j); break; }
            }
        }
    }
}

// K3: compact candidates (top16 >= P) with wave-aggregated counter atomics.
__global__ __launch_bounds__(256) void k_compact(const float* __restrict__ logits,
                                                 const float* __restrict__ scores,
                                                 const unsigned* __restrict__ P,
                                                 unsigned* __restrict__ ctr,
                                                 unsigned long long* __restrict__ cand,
                                                 int A) {
    int img = blockIdx.y;
    unsigned p = P[img];
    int lane = threadIdx.x & 63;
    int nquad = A >> 2;
    for (int q = blockIdx.x * 256 + threadIdx.x; q < nquad; q += NBLK * 256) {
        float sv[4];
        if (scores) {
            float4 t = ((const float4*)(scores + (size_t)img * A))[q];
            sv[0] = t.x; sv[1] = t.y; sv[2] = t.z; sv[3] = t.w;
        } else {
            const float* lp = logits + ((size_t)img * A + (size_t)q * 4) * NCLS;
            float f[40];
#pragma unroll
            for (int i = 0; i < 10; ++i) ((float4*)f)[i] = ((const float4*)lp)[i];
#pragma unroll
            for (int j = 0; j < 4; ++j) {
                float m = f[10 * j];
#pragma unroll
                for (int c = 1; c < 10; ++c) m = fmaxf(m, f[10 * j + c]);
                float sc = sigmoidf_(m);
                sv[j] = (sc > 0.05f) ? sc : 0.0f;
            }
        }
#pragma unroll
        for (int j = 0; j < 4; ++j) {
            unsigned bits = __float_as_uint(sv[j]);
            bool take = (bits >> 16) >= p;
            unsigned long long mask = __ballot(take);
            if (mask) {
                int cnt = __popcll(mask);
                int leader = __ffsll((unsigned long long)mask) - 1;
                unsigned pos = 0;
                if (lane == leader) pos = atomicAdd(&ctr[img], (unsigned)cnt);
                pos = (unsigned)__shfl((int)pos, leader);
                if (take) {
                    unsigned slot = pos + (unsigned)__popcll(mask & ((1ull << lane) - 1ull));
                    if (slot < CANDMAX) {
                        unsigned a = (unsigned)(q * 4 + j);
                        cand[(size_t)img * CANDMAX + slot] =
                            ((unsigned long long)bits << 32) | (unsigned)(~a);
                    }
                }
            }
        }
    }
    int tail0 = nquad << 2;
    if (blockIdx.x == 0) {
        for (int a = tail0 + (int)threadIdx.x; a < A; a += 256) {
            float sc;
            if (scores) sc = scores[(size_t)img * A + a];
            else {
                const float* lp = logits + ((size_t)img * A + a) * NCLS;
                float m = lp[0];
                for (int c = 1; c < 10; ++c) m = fmaxf(m, lp[c]);
                float s = sigmoidf_(m);
                sc = (s > 0.05f) ? s : 0.0f;
            }
            unsigned bits = __float_as_uint(sc);
            if ((bits >> 16) >= p) {
                unsigned pos = atomicAdd(&ctr[img], 1u);
                if (pos < CANDMAX)
                    cand[(size_t)img * CANDMAX + pos] =
                        ((unsigned long long)bits << 32) | (unsigned)(~a);
            }
        }
    }
}

// K4+K5 fused: sort -> decode -> soft-NMS with FLOAT-TOLERANT BATCHED picks.
// Batch validity (proof sketch): scores only decay. If at batch start no
// active non-member y beats (m_cf[7], m_idx[7]) under (score desc, idx asc),
// then no y beats any (m_cf[i], m_idx[i]) at its step: y's step score <= start
// score < m_cf[7] <= m_cf[i] (strict case); equality case forces idx_y >
// m_idx[7] >= m_idx[i] among tied scores (merged list ascending idx), so the
// member wins argmax ties. Members are not decayed intra-batch (hot-pair
// ballot == 0 required), so their step scores equal m_cf. Bail -> one
// sequential pick (proven round-7 body) and retry.
__global__ __launch_bounds__(512) void k_sortnms(const unsigned long long* __restrict__ cand,
                                                 const unsigned* __restrict__ ctr,
                                                 const float* __restrict__ logits,
                                                 const float* __restrict__ rel,
                                                 const float* __restrict__ anch,
                                                 float* __restrict__ out, int A, int B) {
    __shared__ unsigned long long key[CANDMAX];
    __shared__ float s_box[TOPK][4];
    __shared__ int   s_lab[TOPK];
    __shared__ float s_pbox[TOPK][4];
    __shared__ int   s_plab[TOPK];
    __shared__ float s_psc[TOPK];
    __shared__ int   s_alive[TOPK];

    const float CLIPV = 4.135166556742356f;  // log(1000/16)
    const float EPS = 1e-7f;
    const float W_ = 1333.0f, H_ = 800.0f;

    int img = blockIdx.x;
    int tid = threadIdx.x;

    // ---- sort phase (512 threads) ----
    unsigned n = ctr[img];
    if (n > CANDMAX) n = CANDMAX;
    int L = (n <= 1024) ? 1024 : (n <= 2048) ? 2048 : CANDMAX;
    for (int i = tid; i < L; i += 512)
        key[i] = (i < (int)n) ? ~cand[(size_t)img * CANDMAX + i] : ~0ull;
    __syncthreads();
    for (int k = 2; k <= L; k <<= 1) {
        for (int j = k >> 1; j > 0; j >>= 1) {
            for (int i = tid; i < L; i += 512) {
                int l = i ^ j;
                if (l > i) {
                    unsigned long long va = key[i], vb = key[l];
                    bool up = ((i & k) == 0);
                    if (up ? (va > vb) : (va < vb)) { key[i] = vb; key[l] = va; }
                }
            }
            __syncthreads();
        }
    }
    for (int i = L + tid; i < CANDMAX; i += 512) key[i] = ~0ull;
    __syncthreads();

    // ---- Phase A: decode top-1000 into LDS ----
    for (int t2 = tid; t2 < TOPK; t2 += 512) {
        unsigned long long ik = key[t2];
        unsigned ai = (unsigned)ik;
        if (ai >= (unsigned)A) ai = 0;
        const float* lp = logits + ((size_t)img * A + ai) * NCLS;
        float best = sigmoidf_(lp[0]); int lbb = 0;
#pragma unroll
        for (int cc = 1; cc < NCLS; ++cc) {
            float v = sigmoidf_(lp[cc]);
            if (v > best) { best = v; lbb = cc; }
        }
        const float* rp = rel + ((size_t)img * A + ai) * 4;
        const float* ap = anch + (size_t)ai * 4;
        float a0 = ap[0], a1 = ap[1], a2 = ap[2], a3 = ap[3];
        float wa = a2 - a0, ha = a3 - a1;
        float cxa = a0 + 0.5f * wa, cya = a1 + 0.5f * ha;
        float dx = rp[0], dy = rp[1];
        float dw = fminf(rp[2], CLIPV), dh = fminf(rp[3], CLIPV);
        float cx = dx * wa + cxa, cy = dy * ha + cya;
        float w = expf(dw) * wa, h = expf(dh) * ha;
        s_box[t2][0] = fminf(fmaxf(cx - 0.5f * w, 0.0f), W_);
        s_box[t2][1] = fminf(fmaxf(cy - 0.5f * h, 0.0f), H_);
        s_box[t2][2] = fminf(fmaxf(cx + 0.5f * w, 0.0f), W_);
        s_box[t2][3] = fminf(fmaxf(cy + 0.5f * h, 0.0f), H_);
        s_lab[t2] = lbb;
    }
    __syncthreads();
    if (tid >= 64) return;          // wave 0 only from here
    int lane = tid;

    int M = TOPK;
    int need_full = 0;
    float bound = key_score(key, ACTK);

    // ================= FAST ATTEMPT: batched picks over top-256 ==============
    {
        float sc[4], x1[4], y1[4], x2[4], y2[4], ar[4];
        int lb[4];
#pragma unroll
        for (int j = 0; j < 4; ++j) {
            int c = lane + (j << 6);
            float4 bb = *(const float4*)&s_box[c][0];
            x1[j] = bb.x; y1[j] = bb.y; x2[j] = bb.z; y2[j] = bb.w;
            ar[j] = (bb.z - bb.x) * (bb.w - bb.y);
            lb[j] = s_lab[c];
            sc[j] = key_score(key, c);
        }
        unsigned long long skip0 = 0, skip1 = 0, skip2 = 0, skip3 = 0;
        int t = 0, nconf = 0, Mf = -1;

        while (t < ACTK) {
            // ---- rank-select: lane r gets the r-th clear (clean) index ----
            unsigned long long m0 = ~skip0, m1 = ~skip1, m2 = ~skip2, m3 = ~skip3;
            int c0 = __popcll(m0), c01 = c0 + __popcll(m1);
            int c012 = c01 + __popcll(m2), c0123 = c012 + __popcll(m3);
            int r = lane; unsigned long long mw = 0; int base = ACTK;
            if (r < c0) { mw = m0; base = 0; }
            else if (r < c01) { mw = m1; base = 64; r -= c0; }
            else if (r < c012) { mw = m2; base = 128; r -= c01; }
            else if (r < c0123) { mw = m3; base = 192; r -= c012; }
            int myf = ACTK;
            if (base < ACTK) {
                unsigned lo = (unsigned)mw; int pc = __popc(lo); unsigned cur; int off = 0;
                if (r >= pc) { cur = (unsigned)(mw >> 32); off = 32; r -= pc; } else cur = lo;
                int pq = __popc(cur & 0xFFFFu); if (r >= pq) { cur >>= 16; off += 16; r -= pq; }
                pq = __popc(cur & 0xFFu); if (r >= pq) { cur >>= 8; off += 8; r -= pq; }
                pq = __popc(cur & 0xFu); if (r >= pq) { cur >>= 4; off += 4; r -= pq; }
                pq = __popc(cur & 0x3u); if (r >= pq) { cur >>= 2; off += 2; r -= pq; }
                pq = __popc(cur & 0x1u); if (r >= pq) { off += 1; }
                myf = base + off;
            }
            int fcl[8];
#pragma unroll
            for (int i = 0; i < 8; ++i) fcl[i] = __shfl(myf, i);
            int f = fcl[0];
            bool did_batch = false;

            if (fcl[7] < ACTK && t + 8 <= ACTK) {
                float cfc[8];
#pragma unroll
                for (int i = 0; i < 8; ++i) cfc[i] = key_score(key, fcl[i]);
                // exclusion vs clean list + per-lane best among non-members
                bool isC[4]; float bvx = -3.0f; int bix = 0x7FFFFFFF;
#pragma unroll
                for (int j = 0; j < 4; ++j) {
                    int c = lane + (j << 6);
                    bool m_ = false;
#pragma unroll
                    for (int i = 0; i < 8; ++i) m_ = m_ || (c == fcl[i]);
                    isC[j] = m_;
                    float v = m_ ? -3.0f : sc[j];
                    if (v > bvx) { bvx = v; bix = c; }
                }
                bool beat0 = (bvx > cfc[7]) || (bvx == cfc[7] && bix < fcl[7]);
                unsigned long long fm = __ballot(beat0);
                int nf = __popcll(fm);
                if (nf <= 2) {
                    int m_idx[8]; float m_cf[8];
                    bool isM[4];
                    bool ok = true;
                    if (nf == 0) {
#pragma unroll
                        for (int i = 0; i < 8; ++i) { m_idx[i] = fcl[i]; m_cf[i] = cfc[i]; }
#pragma unroll
                        for (int j = 0; j < 4; ++j) isM[j] = isC[j];
                    } else {
                        int l1 = __ffsll(fm) - 1;
                        unsigned long long fm2 = fm & (fm - 1);
                        float fvA = __shfl(bvx, l1); int fxA = __shfl(bix, l1);
                        float fvB = 0.0f; int fxB = 0;
                        if (nf == 2) {
                            int l2 = __ffsll(fm2) - 1;
                            fvB = __shfl(bvx, l2); fxB = __shfl(bix, l2);
                            bool ab = (fvA > fvB) || (fvA == fvB && fxA < fxB);
                            if (!ab) { float tv = fvA; fvA = fvB; fvB = tv;
                                       int ti = fxA; fxA = fxB; fxB = ti; }
                        }
                        int pA = 0;
#pragma unroll
                        for (int i = 0; i < 8; ++i)
                            pA += ((cfc[i] > fvA) || (cfc[i] == fvA && fcl[i] < fxA)) ? 1 : 0;
                        if (nf == 1) {
#pragma unroll
                            for (int k = 0; k < 8; ++k) {
                                const int km1 = (k >= 1) ? (k - 1) : 0;
                                m_idx[k] = (k < pA) ? fcl[k] : ((k == pA) ? fxA : fcl[km1]);
                                m_cf[k]  = (k < pA) ? cfc[k] : ((k == pA) ? fvA : cfc[km1]);
                            }
                        } else {
                            int pBp = 0;
#pragma unroll
                            for (int i = 0; i < 8; ++i)
                                pBp += ((cfc[i] > fvB) || (cfc[i] == fvB && fcl[i] < fxB)) ? 1 : 0;
                            int pB = pBp + 1;   // A ranks before B always
#pragma unroll
                            for (int k = 0; k < 8; ++k) {
                                const int km1 = (k >= 1) ? (k - 1) : 0;
                                const int km2 = (k >= 2) ? (k - 2) : 0;
                                int idxv; float cfv_;
                                if (k < pA)       { idxv = fcl[k];  cfv_ = cfc[k]; }
                                else if (k == pA) { idxv = fxA;     cfv_ = fvA; }
                                else if (k < pB)  { idxv = fcl[km1]; cfv_ = cfc[km1]; }
                                else if (k == pB) { idxv = fxB;     cfv_ = fvB; }
                                else              { idxv = fcl[km2]; cfv_ = cfc[km2]; }
                                m_idx[k] = idxv; m_cf[k] = cfv_;
                            }
                        }
                        ok = (m_cf[7] >= bound);   // excluded (>=256) can't win
                        // re-exclusion + re-ballot against merged list
                        float bvy = -3.0f; int biy = 0x7FFFFFFF;
#pragma unroll
                        for (int j = 0; j < 4; ++j) {
                            int c = lane + (j << 6);
                            bool m_ = false;
#pragma unroll
                            for (int i = 0; i < 8; ++i) m_ = m_ || (c == m_idx[i]);
                            isM[j] = m_;
                            float v = m_ ? -3.0f : sc[j];
                            if (v > bvy) { bvy = v; biy = c; }
                        }
                        bool beat1 = (bvy > m_cf[7]) || (bvy == m_cf[7] && biy < m_idx[7]);
                        ok = ok && (__ballot(beat1) == 0ull);
                    }
                    if (ok) {
                        // prior-pick loads (issued early; land under pair phase)
                        float4 qb[4]; int ga[4];
#pragma unroll
                        for (int k = 0; k < 4; ++k) {
                            int p = lane + (k << 6);
                            int pc2 = (p < t) ? p : 0;
                            qb[k] = *(const float4*)&s_pbox[pc2][0];
                            ga[k] = (p < t) ? s_alive[pc2] : 0;
                        }
                        float4 mbx[8]; int mlb[8];
#pragma unroll
                        for (int i = 0; i < 8; ++i) {
                            mbx[i] = *(const float4*)&s_box[m_idx[i]][0];
                            mlb[i] = s_lab[m_idx[i]];
                        }
                        // 8x8 pair phase: lane = pi*8+pj
                        int pi = lane >> 3, pj = lane & 7;
                        int fa = m_idx[0], fbq = m_idx[0];
#pragma unroll
                        for (int i = 1; i < 8; ++i) {
                            fa = (pi == i) ? m_idx[i] : fa;
                            fbq = (pj == i) ? m_idx[i] : fbq;
                        }
                        float4 pba = *(const float4*)&s_box[fa][0];
                        float4 pbb = *(const float4*)&s_box[fbq][0];
                        int pla = s_lab[fa], plbq = s_lab[fbq];
                        float lxp = fmaxf(pba.x, pbb.x), lyp = fmaxf(pba.y, pbb.y);
                        float rxp = fminf(pba.z, pbb.z), ryp = fminf(pba.w, pbb.w);
                        float iwp = fmaxf(rxp - lxp, 0.0f), ihp = fmaxf(ryp - lyp, 0.0f);
                        float interp = iwp * ihp;
                        float aap = (pba.z - pba.x) * (pba.w - pba.y);
                        float abp = (pbb.z - pbb.x) * (pbb.w - pbb.y);
                        float ioup = interp / (aap + abp - interp + EPS);
                        bool offd = (pi != pj);
                        unsigned long long hotm = __ballot(offd && interp > 0.0f && pla == plbq);
                        unsigned long long supm = __ballot(offd && ioup > 0.8f);
                        if (hotm == 0ull) {     // no intra-batch decay -> valid
                            // greedy vs prior picks per member
                            unsigned supP = 0;
#pragma unroll
                            for (int i = 0; i < 8; ++i) {
                                bool s_ = false;
#pragma unroll
                                for (int k = 0; k < 4; ++k) {
                                    if (ga[k]) {
                                        float lx = fmaxf(mbx[i].x, qb[k].x), ly = fmaxf(mbx[i].y, qb[k].y);
                                        float rx = fminf(mbx[i].z, qb[k].z), ry = fminf(mbx[i].w, qb[k].w);
                                        float iw = fmaxf(rx - lx, 0.0f), ih = fmaxf(ry - ly, 0.0f);
                                        float inter = iw * ih;
                                        float pa = (mbx[i].z - mbx[i].x) * (mbx[i].w - mbx[i].y);
                                        float qa = (qb[k].z - qb[k].x) * (qb[k].w - qb[k].y);
                                        float iou = inter / (pa + qa - inter + EPS);
                                        s_ = s_ || (iou > 0.8f);
                                    }
                                }
                                if (__ballot(s_) != 0ull) supP |= (1u << i);
                            }
                            // aliveness (uniform mask algebra) + writes + cut
                            unsigned long long aliveExp = 0ull; int cut = -1;
#pragma unroll
                            for (int i = 0; i < 8; ++i) {
                                if (cut < 0) {
                                    float pscI = fmaxf(m_cf[i], 0.0f);
                                    bool al = (pscI > 0.3f) && !((supP >> i) & 1u)
                                        && ((supm & (0x0101010101010101ull << i) & aliveExp) == 0ull);
                                    if (lane == 0) {
                                        *(float4*)&s_pbox[t + i][0] = mbx[i];
                                        s_plab[t + i] = mlb[i];
                                        s_psc[t + i] = pscI;
                                        s_alive[t + i] = al ? 1 : 0;
                                    }
                                    if (al) { aliveExp |= (0xFFull << (8 * i)); ++nconf; }
                                    if (nconf >= DETS) cut = i;
                                }
                            }
                            if (cut >= 0) { Mf = t + cut + 1; break; }
                            // decay (pick order preserved per slot) + skip + mark
#pragma unroll
                            for (int j = 0; j < 4; ++j) {
                                float sj = sc[j];
                                unsigned long long acc = 0ull;
#pragma unroll
                                for (int i = 0; i < 8; ++i) {
                                    float lx = fmaxf(mbx[i].x, x1[j]), ly = fmaxf(mbx[i].y, y1[j]);
                                    float rx = fminf(mbx[i].z, x2[j]), ry = fminf(mbx[i].w, y2[j]);
                                    float iw = fmaxf(rx - lx, 0.0f), ih = fmaxf(ry - ly, 0.0f);
                                    float inter = iw * ih;
                                    bool hot = (inter > 0.0f) && (lb[j] == mlb[i]);
                                    unsigned long long hm = __ballot(hot);
                                    if (hm != 0ull) {
                                        float wax = (mbx[i].z - mbx[i].x) * (mbx[i].w - mbx[i].y);
                                        float iou2 = inter / (wax + ar[j] - inter + EPS);
                                        float ie = (lb[j] == mlb[i]) ? iou2 : 0.0f;
                                        sj *= expf(-(ie * ie) / 0.5f);
                                    }
                                    acc |= hm;
                                }
                                sc[j] = isM[j] ? -1.0f : sj;
                                if (j == 0) skip0 |= acc; else if (j == 1) skip1 |= acc;
                                else if (j == 2) skip2 |= acc; else skip3 |= acc;
                            }
#pragma unroll
                            for (int i = 0; i < 8; ++i) {
                                int w2 = m_idx[i] >> 6;
                                unsigned long long b = 1ull << (m_idx[i] & 63);
                                if (w2 == 0) skip0 |= b; else if (w2 == 1) skip1 |= b;
                                else if (w2 == 2) skip2 |= b; else skip3 |= b;
                            }
                            t += 8;
                            did_batch = true;
                        }
                    }
                }
            }
            if (did_batch) continue;

            // ======== sequential single pick (round-7 proven body) ========
            float cf; float4 fb = make_float4(0, 0, 0, 0); int flab = 0;
            if (f < ACTK) { cf = key_score(key, f); fb = *(const float4*)&s_box[f][0]; flab = s_lab[f]; }
            else cf = -0.5f;
            float bv = sc[0]; int bi = lane;
#pragma unroll
            for (int j = 1; j < 4; ++j) {
                int e = lane + (j << 6);
                if (sc[j] > bv) { bv = sc[j]; bi = e; }
            }
            bool beat = (f < ACTK) ? (bv > cf || (bv == cf && bi < f)) : (bv > -0.5f);
            unsigned long long bb2 = __ballot(beat);
            int pick; float pcur; float4 pb; int plab_;
            if (bb2 == 0ull) {
                if (f >= ACTK) { need_full = 1; break; }   // degenerate
                pick = f; pcur = cf; pb = fb; plab_ = flab;
            } else {
                float rv = bv; int ri = bi;
#pragma unroll
                for (int d = 32; d; d >>= 1) {
                    float ov = __shfl_xor(rv, d);
                    int oi = __shfl_xor(ri, d);
                    if (ov > rv || (ov == rv && oi < ri)) { rv = ov; ri = oi; }
                }
                pick = ri; pcur = rv;
                pb = *(const float4*)&s_box[pick][0];
                plab_ = s_lab[pick];
                if (!(pcur >= bound)) { need_full = 1; break; }
            }
            float psc = fmaxf(pcur, 0.0f);
            if (lane == 0) {
                *(float4*)&s_pbox[t][0] = pb;
                s_plab[t] = plab_;
                s_psc[t] = psc;
            }
            float4 qb[4]; int ga[4];
#pragma unroll
            for (int k = 0; k < 4; ++k) {
                int p = lane + (k << 6);
                int pc2 = (p < t) ? p : 0;
                qb[k] = *(const float4*)&s_pbox[pc2][0];
                ga[k] = (p < t) ? s_alive[pc2] : 0;
            }
            float wax = (pb.z - pb.x) * (pb.w - pb.y);
#pragma unroll
            for (int j = 0; j < 4; ++j) {
                float lx2 = fmaxf(pb.x, x1[j]), ly2 = fmaxf(pb.y, y1[j]);
                float rx2 = fminf(pb.z, x2[j]), ry2 = fminf(pb.w, y2[j]);
                float iw2 = fmaxf(rx2 - lx2, 0.0f), ih2 = fmaxf(ry2 - ly2, 0.0f);
                float inter2 = iw2 * ih2;
                bool hot = (inter2 > 0.0f) && (lb[j] == plab_);
                unsigned long long hm = __ballot(hot);
                if (hm != 0ull) {
                    float iou2 = inter2 / (wax + ar[j] - inter2 + EPS);
                    float ie = (lb[j] == plab_) ? iou2 : 0.0f;
                    sc[j] *= expf(-(ie * ie) / 0.5f);
                }
                if (j == 0) skip0 |= hm; else if (j == 1) skip1 |= hm;
                else if (j == 2) skip2 |= hm; else skip3 |= hm;
            }
#pragma unroll
            for (int j = 0; j < 4; ++j)
                if (lane + (j << 6) == pick) sc[j] = -1.0f;
            {
                int w2 = pick >> 6;
                unsigned long long b = 1ull << (pick & 63);
                if (w2 == 0) skip0 |= b; else if (w2 == 1) skip1 |= b;
                else if (w2 == 2) skip2 |= b; else skip3 |= b;
            }
            bool sup = false;
#pragma unroll
            for (int k = 0; k < 4; ++k) {
                if (ga[k]) {
                    float lx = fmaxf(pb.x, qb[k].x), ly = fmaxf(pb.y, qb[k].y);
                    float rx = fminf(pb.z, qb[k].z), ry = fminf(pb.w, qb[k].w);
                    float iw = fmaxf(rx - lx, 0.0f), ih = fmaxf(ry - ly, 0.0f);
                    float inter = iw * ih;
                    float qa = (qb[k].z - qb[k].x) * (qb[k].w - qb[k].y);
                    float iou = inter / (wax + qa - inter + EPS);
                    sup = sup || (iou > 0.8f);
                }
            }
            bool alive = (psc > 0.3f) && (__ballot(sup) == 0ull);
            if (lane == 0) s_alive[t] = alive ? 1 : 0;
            nconf += alive ? 1 : 0;
            ++t;
            if (nconf >= DETS) { Mf = t; break; }
        }
        if (Mf >= 0) M = Mf; else need_full = 1;
    }

    // ================= FULL FALLBACK: verbatim 16-slot loop =================
    if (need_full) {
        float sc[SLOTS], x1[SLOTS], y1[SLOTS], x2[SLOTS], y2[SLOTS], ar[SLOTS];
        int lb[SLOTS];
#pragma unroll
        for (int j = 0; j < SLOTS; ++j) {
            int c = lane + (j << 6);
            if (c < TOPK) {
                float4 bb = *(const float4*)&s_box[c][0];
                x1[j] = bb.x; y1[j] = bb.y; x2[j] = bb.z; y2[j] = bb.w;
                ar[j] = (bb.z - bb.x) * (bb.w - bb.y);
                lb[j] = s_lab[c];
                sc[j] = key_score(key, c);
            } else {
                sc[j] = -2.0f; lb[j] = -1;
                x1[j] = y1[j] = x2[j] = y2[j] = ar[j] = 0.0f;
            }
        }
        unsigned long long aw = 0;
        if (lane < 15) aw = ~0ull;
        else if (lane == 15) aw = (1ull << (TOPK - 15 * 64)) - 1;
        int f = 0, nconf = 0;
        M = TOPK;
        for (int t = 0; t < TOPK; ++t) {
            int fp = (f < TOPK) ? f : 0;
            float4 fb = *(const float4*)&s_box[fp][0];
            int flab = s_lab[fp];
            int fs = f >> 6;
            float v = sc[0];
#pragma unroll
            for (int j = 1; j < SLOTS; ++j) if (fs == j) v = sc[j];
            float cf = __shfl(v, f & 63);
            float lm = sc[0];
#pragma unroll
            for (int j = 1; j < SLOTS; ++j) lm = fmaxf(lm, sc[j]);
            int pick; float pcur; float4 pb; int plab_;
            unsigned long long bb2 = __ballot(lm > cf);
            if (bb2 == 0) {
                pick = f; pcur = cf; pb = fb; plab_ = flab;
            } else {
                float bv = sc[0]; int bi = lane;
#pragma unroll
                for (int j = 1; j < SLOTS; ++j) {
                    int e = lane + (j << 6);
                    if (sc[j] > bv) { bv = sc[j]; bi = e; }
                }
#pragma unroll
                for (int d = 32; d; d >>= 1) {
                    float ov = __shfl_xor(bv, d);
                    int oi = __shfl_xor(bi, d);
                    if (ov > bv || (ov == bv && oi < bi)) { bv = ov; bi = oi; }
                }
                pick = bi; pcur = bv;
                pb = *(const float4*)&s_box[pick][0];
                plab_ = s_lab[pick];
            }
            float psc = fmaxf(pcur, 0.0f);
            if (lane == 0) {
                *(float4*)&s_pbox[t][0] = pb;
                s_plab[t] = plab_;
                s_psc[t] = psc;
            }
            bool alive = (psc > 0.3f);
            if (alive && t > 0) {
                float pa = (pb.z - pb.x) * (pb.w - pb.y);
                int kprev = ((t - 1) >> 6) + 1;
                bool sup = false;
                for (int k = 0; k < kprev; ++k) {
                    int p = lane + (k << 6);
                    int pc = (p < t) ? p : 0;
                    float4 qb = *(const float4*)&s_pbox[pc][0];
                    int ga = s_alive[pc];
                    if (p < t && ga) {
                        float lx = fmaxf(pb.x, qb.x), ly = fmaxf(pb.y, qb.y);
                        float rx = fminf(pb.z, qb.z), ry = fminf(pb.w, qb.w);
                        float iw = fmaxf(rx - lx, 0.0f), ih = fmaxf(ry - ly, 0.0f);
                        float inter = iw * ih;
                        float qa = (qb.z - qb.x) * (qb.w - qb.y);
                        float iou = inter / (pa + qa - inter + EPS);
                        sup = sup || (iou > 0.8f);
                    }
                }
                alive = (__ballot(sup) == 0ull);
            }
            if (lane == 0) s_alive[t] = alive ? 1 : 0;
            nconf += alive ? 1 : 0;
            if (nconf >= DETS) { M = t + 1; break; }
            float wax = (pb.z - pb.x) * (pb.w - pb.y);
#pragma unroll
            for (int j = 0; j < SLOTS; ++j) {
                float lx2 = fmaxf(pb.x, x1[j]), ly2 = fmaxf(pb.y, y1[j]);
                float rx2 = fminf(pb.z, x2[j]), ry2 = fminf(pb.w, y2[j]);
                float iw2 = fmaxf(rx2 - lx2, 0.0f), ih2 = fmaxf(ry2 - ly2, 0.0f);
                float inter2 = iw2 * ih2;
                bool hot = (inter2 > 0.0f) && (lb[j] == plab_);
                if (__ballot(hot) != 0ull) {
                    float iou2 = inter2 / (wax + ar[j] - inter2 + EPS);
                    float ie = (lb[j] == plab_) ? iou2 : 0.0f;
                    sc[j] *= expf(-(ie * ie) / 0.5f);
                }
            }
#pragma unroll
            for (int j = 0; j < SLOTS; ++j)
                if (lane + (j << 6) == pick) sc[j] = -1.0f;
            if (lane == (pick >> 6)) aw &= ~(1ull << (pick & 63));
            if (pick == f) {
                int fw = f >> 6;
                unsigned long long w2 = __shfl(aw, fw);
                while (w2 == 0ull && fw < 15) { ++fw; w2 = __shfl(aw, fw); }
                f = (w2 == 0ull) ? TOPK : (fw << 6) + (__ffsll(w2) - 1);
            }
        }
    }

    // ---- emit: alive picks in pick order, then dead padding if needed ----
    float* out_boxes  = out;
    float* out_scores = out + (size_t)B * DETS * 4;
    float* out_labels = out + (size_t)B * DETS * 5;
    int kmax = (M + 63) >> 6;
    int base = 0;
    for (int k = 0; k < kmax; ++k) {
        int p = lane + (k << 6);
        bool av = (p < M) && (s_alive[p] != 0);
        unsigned long long mask = __ballot(av);
        int slot = base + (int)__popcll(mask & ((1ull << lane) - 1ull));
        if (av && slot < DETS) {
            float4 pb = *(const float4*)&s_pbox[p][0];
            float* ob = out_boxes + ((size_t)img * DETS + slot) * 4;
            ob[0] = pb.x; ob[1] = pb.y; ob[2] = pb.z; ob[3] = pb.w;
            out_scores[img * DETS + slot] = s_psc[p];
            out_labels[img * DETS + slot] = (float)s_plab[p];
        }
        base += (int)__popcll(mask);
    }
    if (base < DETS) {
        int dbase = 0;
        for (int k = 0; k < kmax; ++k) {
            int p = lane + (k << 6);
            bool dd = (p < M) && (s_alive[p] == 0);
            unsigned long long mask = __ballot(dd);
            int slot = base + dbase + (int)__popcll(mask & ((1ull << lane) - 1ull));
            if (dd && slot < DETS) {
                float4 pb = *(const float4*)&s_pbox[p][0];
                float* ob = out_boxes + ((size_t)img * DETS + slot) * 4;
                ob[0] = pb.x; ob[1] = pb.y; ob[2] = pb.z; ob[3] = pb.w;
                out_scores[img * DETS + slot] = -1.0f;
                out_labels[img * DETS + slot] = (float)s_plab[p];
            }
            dbase += (int)__popcll(mask);
        }
    }
}

extern "C" void kernel_launch(void* const* d_in, const int* in_sizes, int n_in,
                              void* d_out, int out_size, void* d_ws, size_t ws_size,
                              hipStream_t stream) {
    const float* logits = (const float*)d_in[0];
    const float* rel = (const float*)d_in[1];
    const float* anch = (const float*)d_in[2];
    float* out = (float*)d_out;

    int A = in_sizes[2] / 4;                 // anchors
    int B = in_sizes[0] / (A * NCLS);        // batch

    // workspace layout: [hist | ctr | done] zeroed in ONE memset, then the rest
    char* w = (char*)d_ws;
    unsigned* hist = (unsigned*)w;           w += (size_t)B * NBINS * 4;
    unsigned* ctr = (unsigned*)w;            w += (size_t)B * 4;
    unsigned* done = (unsigned*)w;           w += (size_t)B * 4;
    size_t zbytes = (size_t)(w - (char*)d_ws);
    unsigned long long* cand = (unsigned long long*)w; w += (size_t)B * CANDMAX * 8;
    unsigned* P = (unsigned*)w;              w += (size_t)B * 4;
    w += 4;                                   // keep 8B alignment headroom
    float* scores = (float*)w;
    size_t used = (size_t)(w - (char*)d_ws);
    int use_scores = (used + (size_t)B * A * 4 <= ws_size) ? 1 : 0;

    hipMemsetAsync(d_ws, 0, zbytes, stream);

    dim3 g1(NBLK, (unsigned)B);
    k_score_hist<<<g1, 256, 0, stream>>>(logits, scores, hist, done, P, A, use_scores);
    k_compact<<<g1, 256, 0, stream>>>(logits, use_scores ? scores : nullptr, P, ctr, cand, A);
    k_sortnms<<<B, 512, 0, stream>>>(cand, ctr, logits, rel, anch, out, A, B);
}

// Round 9
// 275.511 us; speedup vs baseline: 1.1000x; 1.1000x over previous
//
#include <hip/hip_runtime.h>
#include <math.h>

// ---------------- constants from the reference ----------------
#define NCLS 10
#define TOPK 1000
#define DETS 100
#define CANDMAX 4096
#define SLOTS 16   // 16 * 64 lanes = 1024 >= TOPK (full fallback)
#define ACTK 256   // fast-path active set: 4 slots * 64 lanes

// score histogram: scores > 0.05 have (bits>>16) in [0x3D4C, 0x3F80) -> 564 bins
#define BIN0 0x3D4Cu
#define NBINS 576
#define NBLK 64    // blocks per image for the score/compact passes

__device__ __forceinline__ float sigmoidf_(float x) {
    return 1.0f / (1.0f + expf(-x));
}

__device__ __forceinline__ float key_score(const unsigned long long* key, int c) {
    return __uint_as_float(~(unsigned)(key[c] >> 32));
}

// order-isomorphic float<->u32 mapping (total order, bijective)
__device__ __forceinline__ unsigned fkey_(float f) {
    unsigned b = __float_as_uint(f);
    return (b & 0x80000000u) ? ~b : (b | 0x80000000u);
}
__device__ __forceinline__ float funkey_(unsigned k) {
    return __uint_as_float((k & 0x80000000u) ? (k & 0x7FFFFFFFu) : ~k);
}

// 64-lane unsigned max via DPP (row_shr 1/2/4/8 + row_bcast15/31), ~ALU latency.
// Invalid source lanes contribute old=0 (identity for unsigned max).
__device__ __forceinline__ unsigned wave_umax_(unsigned x) {
    unsigned t;
    t = (unsigned)__builtin_amdgcn_update_dpp(0, (int)x, 0x111, 0xF, 0xF, false); x = (x > t) ? x : t;
    t = (unsigned)__builtin_amdgcn_update_dpp(0, (int)x, 0x112, 0xF, 0xF, false); x = (x > t) ? x : t;
    t = (unsigned)__builtin_amdgcn_update_dpp(0, (int)x, 0x114, 0xF, 0xF, false); x = (x > t) ? x : t;
    t = (unsigned)__builtin_amdgcn_update_dpp(0, (int)x, 0x118, 0xF, 0xF, false); x = (x > t) ? x : t;
    t = (unsigned)__builtin_amdgcn_update_dpp(0, (int)x, 0x142, 0xF, 0xF, false); x = (x > t) ? x : t;
    t = (unsigned)__builtin_amdgcn_update_dpp(0, (int)x, 0x143, 0xF, 0xF, false); x = (x > t) ? x : t;
    return (unsigned)__builtin_amdgcn_readlane((int)x, 63);
}

// K1: fused score + per-block LDS histogram (+ score cache) + last-block findP.
__global__ __launch_bounds__(256) void k_score_hist(const float* __restrict__ logits,
                                                    float* __restrict__ scores,
                                                    unsigned* hist,
                                                    unsigned* __restrict__ done,
                                                    unsigned* __restrict__ P,
                                                    int A, int use_scores) {
    __shared__ unsigned h[NBINS];
    __shared__ int s_last;
    int img = blockIdx.y;
    for (int i = threadIdx.x; i < NBINS; i += 256) h[i] = 0;
    __syncthreads();

    const float* base = logits + (size_t)img * A * NCLS;
    int nquad = A >> 2;
    for (int q = blockIdx.x * 256 + threadIdx.x; q < nquad; q += NBLK * 256) {
        const float4* lp = (const float4*)(base + (size_t)q * 40);
        float f[40];
#pragma unroll
        for (int i = 0; i < 10; ++i) ((float4*)f)[i] = lp[i];
        float4 s4;
        float* sv = &s4.x;
#pragma unroll
        for (int j = 0; j < 4; ++j) {
            float m = f[10 * j];
#pragma unroll
            for (int c = 1; c < 10; ++c) m = fmaxf(m, f[10 * j + c]);
            float sc = sigmoidf_(m);
            sc = (sc > 0.05f) ? sc : 0.0f;
            sv[j] = sc;
            if (sc > 0.0f) {
                unsigned bin = (__float_as_uint(sc) >> 16) - BIN0;
                if (bin >= NBINS) bin = NBINS - 1;
                atomicAdd(&h[bin], 1u);
            }
        }
        if (use_scores) ((float4*)(scores + (size_t)img * A))[q] = s4;
    }
    int tail0 = nquad << 2;
    if (blockIdx.x == 0) {
        for (int a = tail0 + (int)threadIdx.x; a < A; a += 256) {
            const float* lp2 = base + (size_t)a * NCLS;
            float m = lp2[0];
            for (int c = 1; c < 10; ++c) m = fmaxf(m, lp2[c]);
            float sc = sigmoidf_(m);
            sc = (sc > 0.05f) ? sc : 0.0f;
            if (use_scores) scores[(size_t)img * A + a] = sc;
            if (sc > 0.0f) {
                unsigned bin = (__float_as_uint(sc) >> 16) - BIN0;
                if (bin >= NBINS) bin = NBINS - 1;
                atomicAdd(&h[bin], 1u);
            }
        }
    }
    __syncthreads();
    for (int i = threadIdx.x; i < NBINS; i += 256) {
        unsigned c = h[i];
        if (c) atomicAdd(&hist[(size_t)img * NBINS + i], c);
    }
    __syncthreads();
    if (threadIdx.x == 0) {
        __threadfence();   // hist atomics ordered before done increment
        unsigned old = atomicAdd(&done[img], 1u);
        s_last = (old == (unsigned)(NBLK - 1)) ? 1 : 0;
    }
    __syncthreads();
    if (s_last && threadIdx.x < 64) {
        int lane = threadIdx.x;
        unsigned* hh = hist + (size_t)img * NBINS;
        unsigned b[9];
        unsigned s = 0;
#pragma unroll
        for (int j = 0; j < 9; ++j) { b[j] = atomicAdd(&hh[lane * 9 + j], 0u); s += b[j]; }
        unsigned suf = s;
#pragma unroll
        for (int d = 1; d < 64; d <<= 1) {
            unsigned o = __shfl_down(suf, d);
            if (lane + d < 64) suf += o;
        }
        unsigned above = __shfl_down(suf, 1);
        if (lane == 63) above = 0;
        if (lane == 0 && suf < (unsigned)TOPK) P[img] = 0u;
        if (above < (unsigned)TOPK && suf >= (unsigned)TOPK) {
            unsigned cum = above;
            for (int j = 8; j >= 0; --j) {
                cum += b[j];
                if (cum >= (unsigned)TOPK) { P[img] = BIN0 + (unsigned)(lane * 9 + j); break; }
            }
        }
    }
}

// K3: compact candidates (top16 >= P) with wave-aggregated counter atomics.
__global__ __launch_bounds__(256) void k_compact(const float* __restrict__ logits,
                                                 const float* __restrict__ scores,
                                                 const unsigned* __restrict__ P,
                                                 unsigned* __restrict__ ctr,
                                                 unsigned long long* __restrict__ cand,
                                                 int A) {
    int img = blockIdx.y;
    unsigned p = P[img];
    int lane = threadIdx.x & 63;
    int nquad = A >> 2;
    for (int q = blockIdx.x * 256 + threadIdx.x; q < nquad; q += NBLK * 256) {
        float sv[4];
        if (scores) {
            float4 t = ((const float4*)(scores + (size_t)img * A))[q];
            sv[0] = t.x; sv[1] = t.y; sv[2] = t.z; sv[3] = t.w;
        } else {
            const float* lp = logits + ((size_t)img * A + (size_t)q * 4) * NCLS;
            float f[40];
#pragma unroll
            for (int i = 0; i < 10; ++i) ((float4*)f)[i] = ((const float4*)lp)[i];
#pragma unroll
            for (int j = 0; j < 4; ++j) {
                float m = f[10 * j];
#pragma unroll
                for (int c = 1; c < 10; ++c) m = fmaxf(m, f[10 * j + c]);
                float sc = sigmoidf_(m);
                sv[j] = (sc > 0.05f) ? sc : 0.0f;
            }
        }
#pragma unroll
        for (int j = 0; j < 4; ++j) {
            unsigned bits = __float_as_uint(sv[j]);
            bool take = (bits >> 16) >= p;
            unsigned long long mask = __ballot(take);
            if (mask) {
                int cnt = __popcll(mask);
                int leader = __ffsll((unsigned long long)mask) - 1;
                unsigned pos = 0;
                if (lane == leader) pos = atomicAdd(&ctr[img], (unsigned)cnt);
                pos = (unsigned)__shfl((int)pos, leader);
                if (take) {
                    unsigned slot = pos + (unsigned)__popcll(mask & ((1ull << lane) - 1ull));
                    if (slot < CANDMAX) {
                        unsigned a = (unsigned)(q * 4 + j);
                        cand[(size_t)img * CANDMAX + slot] =
                            ((unsigned long long)bits << 32) | (unsigned)(~a);
                    }
                }
            }
        }
    }
    int tail0 = nquad << 2;
    if (blockIdx.x == 0) {
        for (int a = tail0 + (int)threadIdx.x; a < A; a += 256) {
            float sc;
            if (scores) sc = scores[(size_t)img * A + a];
            else {
                const float* lp = logits + ((size_t)img * A + a) * NCLS;
                float m = lp[0];
                for (int c = 1; c < 10; ++c) m = fmaxf(m, lp[c]);
                float s = sigmoidf_(m);
                sc = (s > 0.05f) ? s : 0.0f;
            }
            unsigned bits = __float_as_uint(sc);
            if ((bits >> 16) >= p) {
                unsigned pos = atomicAdd(&ctr[img], 1u);
                if (pos < CANDMAX)
                    cand[(size_t)img * CANDMAX + pos] =
                        ((unsigned long long)bits << 32) | (unsigned)(~a);
            }
        }
    }
}

// K4+K5 fused: sort -> decode -> soft-NMS with DPP-argmax picks (exact) ->
// inline incremental greedy NMS -> top-100 emit.
// Every pick: per-lane best over 4 slots -> order-isomorphic u32 key -> DPP
// wave max (~ALU latency; no ds_bpermute on the chain) -> <=4 cheap ballots
// resolve the LOWEST-INDEX winner (smallest slot j, then smallest lane ==
// smallest candidate index: exact jnp.argmax tie semantics). Active-set bound
// guard vs candidates ranked >=256 (scores only decay; ties at the bound go
// to the lower sorted rank = active set). Fallback: proven 16-slot loop.
__global__ __launch_bounds__(1024) void k_sortnms(const unsigned long long* __restrict__ cand,
                                                  const unsigned* __restrict__ ctr,
                                                  const float* __restrict__ logits,
                                                  const float* __restrict__ rel,
                                                  const float* __restrict__ anch,
                                                  float* __restrict__ out, int A, int B) {
    __shared__ unsigned long long key[CANDMAX];
    __shared__ float s_box[TOPK][4];
    __shared__ int   s_lab[TOPK];
    __shared__ float s_pbox[TOPK][4];
    __shared__ int   s_plab[TOPK];
    __shared__ float s_psc[TOPK];
    __shared__ int   s_alive[TOPK];

    const float CLIPV = 4.135166556742356f;  // log(1000/16)
    const float EPS = 1e-7f;
    const float W_ = 1333.0f, H_ = 800.0f;

    int img = blockIdx.x;
    int tid = threadIdx.x;

    // ---- sort phase (1024 threads) ----
    unsigned n = ctr[img];
    if (n > CANDMAX) n = CANDMAX;
    int L = (n <= 1024) ? 1024 : (n <= 2048) ? 2048 : CANDMAX;
    for (int i = tid; i < L; i += 1024)
        key[i] = (i < (int)n) ? ~cand[(size_t)img * CANDMAX + i] : ~0ull;
    __syncthreads();
    for (int k = 2; k <= L; k <<= 1) {
        for (int j = k >> 1; j > 0; j >>= 1) {
            for (int i = tid; i < L; i += 1024) {
                int l = i ^ j;
                if (l > i) {
                    unsigned long long va = key[i], vb = key[l];
                    bool up = ((i & k) == 0);
                    if (up ? (va > vb) : (va < vb)) { key[i] = vb; key[l] = va; }
                }
            }
            __syncthreads();
        }
    }
    for (int i = L + tid; i < CANDMAX; i += 1024) key[i] = ~0ull;
    __syncthreads();

    // ---- Phase A (1024 threads, 1 candidate each): decode into LDS ----
    if (tid < TOPK) {
        unsigned long long ik = key[tid];
        unsigned ai = (unsigned)ik;
        if (ai >= (unsigned)A) ai = 0;
        const float* lp = logits + ((size_t)img * A + ai) * NCLS;
        float best = sigmoidf_(lp[0]); int lbb = 0;
#pragma unroll
        for (int cc = 1; cc < NCLS; ++cc) {
            float v = sigmoidf_(lp[cc]);
            if (v > best) { best = v; lbb = cc; }
        }
        const float* rp = rel + ((size_t)img * A + ai) * 4;
        const float* ap = anch + (size_t)ai * 4;
        float a0 = ap[0], a1 = ap[1], a2 = ap[2], a3 = ap[3];
        float wa = a2 - a0, ha = a3 - a1;
        float cxa = a0 + 0.5f * wa, cya = a1 + 0.5f * ha;
        float dx = rp[0], dy = rp[1];
        float dw = fminf(rp[2], CLIPV), dh = fminf(rp[3], CLIPV);
        float cx = dx * wa + cxa, cy = dy * ha + cya;
        float w = expf(dw) * wa, h = expf(dh) * ha;
        s_box[tid][0] = fminf(fmaxf(cx - 0.5f * w, 0.0f), W_);
        s_box[tid][1] = fminf(fmaxf(cy - 0.5f * h, 0.0f), H_);
        s_box[tid][2] = fminf(fmaxf(cx + 0.5f * w, 0.0f), W_);
        s_box[tid][3] = fminf(fmaxf(cy + 0.5f * h, 0.0f), H_);
        s_lab[tid] = lbb;
    }
    __syncthreads();
    if (tid >= 64) return;          // wave 0 only from here; no more barriers
    int lane = tid;

    int M = TOPK;
    int need_full = 0;
    float bound = key_score(key, ACTK);   // init score of first EXCLUDED cand

    // ================= FAST ATTEMPT: DPP-argmax, 4 slots =================
    {
        float sc[4], x1[4], y1[4], x2[4], y2[4], ar[4];
        int lb[4];
#pragma unroll
        for (int j = 0; j < 4; ++j) {
            int c = lane + (j << 6);
            float4 bb = *(const float4*)&s_box[c][0];
            x1[j] = bb.x; y1[j] = bb.y; x2[j] = bb.z; y2[j] = bb.w;
            ar[j] = (bb.z - bb.x) * (bb.w - bb.y);
            lb[j] = s_lab[c];
            sc[j] = key_score(key, c);
        }

        int nconf = 0, Mf = -1;

        for (int t = 0; t < ACTK; ++t) {
            // per-lane best (value desc, slot asc => index asc within lane)
            float bv = sc[0]; int bj = 0;
#pragma unroll
            for (int j = 1; j < 4; ++j)
                if (sc[j] > bv) { bv = sc[j]; bj = j; }
            unsigned mk = fkey_(bv);
            unsigned mx = wave_umax_(mk);          // uniform SGPR result
            float pcur = funkey_(mx);

            // active-set guard: excluded (rank>=256) all have score <= bound;
            // equality resolves to the active set (lower sorted rank).
            if (!(pcur >= bound)) { need_full = 1; break; }

            // lowest-index winner: smallest slot j, then smallest lane
            int pick = -1;
#pragma unroll
            for (int jj = 0; jj < 4; ++jj) {
                if (pick < 0) {
                    unsigned long long mj = __ballot(mk == mx && bj == jj);
                    if (mj) pick = (jj << 6) + (__ffsll(mj) - 1);
                }
            }

            float psc = fmaxf(pcur, 0.0f);
            float4 pb = *(const float4*)&s_box[pick][0];
            int plab_ = s_lab[pick];
            if (lane == 0) {
                *(float4*)&s_pbox[t][0] = pb;
                s_plab[t] = plab_;
                s_psc[t] = psc;
            }

            // ---- greedy loads issued early (static unroll, clamped addrs) ----
            float4 qb[4]; int ga[4];
#pragma unroll
            for (int k = 0; k < 4; ++k) {
                int p = lane + (k << 6);
                int pc2 = (p < t) ? p : 0;
                qb[k] = *(const float4*)&s_pbox[pc2][0];
                ga[k] = (p < t) ? s_alive[pc2] : 0;
            }

            // ---- decay (ballot-skip: divide+expf only when a lane is hot) ----
            float wax = (pb.z - pb.x) * (pb.w - pb.y);
#pragma unroll
            for (int j = 0; j < 4; ++j) {
                float lx2 = fmaxf(pb.x, x1[j]), ly2 = fmaxf(pb.y, y1[j]);
                float rx2 = fminf(pb.z, x2[j]), ry2 = fminf(pb.w, y2[j]);
                float iw2 = fmaxf(rx2 - lx2, 0.0f), ih2 = fmaxf(ry2 - ly2, 0.0f);
                float inter2 = iw2 * ih2;
                bool hot = (inter2 > 0.0f) && (lb[j] == plab_);
                if (__ballot(hot) != 0ull) {
                    float iou2 = inter2 / (wax + ar[j] - inter2 + EPS);
                    float ie = (lb[j] == plab_) ? iou2 : 0.0f;
                    sc[j] *= expf(-(ie * ie) / 0.5f);
                }
                // skipped slots/lanes: factor would be expf(-0.0f)==1.0f exactly
            }
            // mark picked (after decay, matching the verified ordering)
#pragma unroll
            for (int j = 0; j < 4; ++j)
                if (lane + (j << 6) == pick) sc[j] = -1.0f;

            // ---- greedy compares + ballot (loads landed under decay) ----
            bool sup = false;
#pragma unroll
            for (int k = 0; k < 4; ++k) {
                if (ga[k]) {
                    float lx = fmaxf(pb.x, qb[k].x), ly = fmaxf(pb.y, qb[k].y);
                    float rx = fminf(pb.z, qb[k].z), ry = fminf(pb.w, qb[k].w);
                    float iw = fmaxf(rx - lx, 0.0f), ih = fmaxf(ry - ly, 0.0f);
                    float inter = iw * ih;
                    float qa = (qb[k].z - qb[k].x) * (qb[k].w - qb[k].y);
                    float iou = inter / (wax + qa - inter + EPS);
                    sup = sup || (iou > 0.8f);
                }
            }
            bool alive = (psc > 0.3f) && (__ballot(sup) == 0ull);
            if (lane == 0) s_alive[t] = alive ? 1 : 0;
            nconf += alive ? 1 : 0;
            if (nconf >= DETS) { Mf = t + 1; break; }
        }
        if (!need_full) {
            if (Mf < 0) need_full = 1;   // exhausted 256 picks with <100 dets
            else M = Mf;
        }
    }

    // ================= FULL FALLBACK: verbatim 16-slot loop =================
    if (need_full) {
        float sc[SLOTS], x1[SLOTS], y1[SLOTS], x2[SLOTS], y2[SLOTS], ar[SLOTS];
        int lb[SLOTS];
#pragma unroll
        for (int j = 0; j < SLOTS; ++j) {
            int c = lane + (j << 6);
            if (c < TOPK) {
                float4 bb = *(const float4*)&s_box[c][0];
                x1[j] = bb.x; y1[j] = bb.y; x2[j] = bb.z; y2[j] = bb.w;
                ar[j] = (bb.z - bb.x) * (bb.w - bb.y);
                lb[j] = s_lab[c];
                sc[j] = key_score(key, c);
            } else {
                sc[j] = -2.0f; lb[j] = -1;
                x1[j] = y1[j] = x2[j] = y2[j] = ar[j] = 0.0f;
            }
        }
        unsigned long long aw = 0;
        if (lane < 15) aw = ~0ull;
        else if (lane == 15) aw = (1ull << (TOPK - 15 * 64)) - 1;
        int f = 0, nconf = 0;
        M = TOPK;
        for (int t = 0; t < TOPK; ++t) {
            int fp = (f < TOPK) ? f : 0;
            float4 fb = *(const float4*)&s_box[fp][0];
            int flab = s_lab[fp];
            int fs = f >> 6;
            float v = sc[0];
#pragma unroll
            for (int j = 1; j < SLOTS; ++j) if (fs == j) v = sc[j];
            float cf = __shfl(v, f & 63);
            float lm = sc[0];
#pragma unroll
            for (int j = 1; j < SLOTS; ++j) lm = fmaxf(lm, sc[j]);
            int pick; float pcur; float4 pb; int plab_;
            unsigned long long bb2 = __ballot(lm > cf);
            if (bb2 == 0) {
                pick = f; pcur = cf; pb = fb; plab_ = flab;
            } else {
                float bv = sc[0]; int bi = lane;
#pragma unroll
                for (int j = 1; j < SLOTS; ++j) {
                    int e = lane + (j << 6);
                    if (sc[j] > bv) { bv = sc[j]; bi = e; }
                }
#pragma unroll
                for (int d = 32; d; d >>= 1) {
                    float ov = __shfl_xor(bv, d);
                    int oi = __shfl_xor(bi, d);
                    if (ov > bv || (ov == bv && oi < bi)) { bv = ov; bi = oi; }
                }
                pick = bi; pcur = bv;
                pb = *(const float4*)&s_box[pick][0];
                plab_ = s_lab[pick];
            }
            float psc = fmaxf(pcur, 0.0f);
            if (lane == 0) {
                *(float4*)&s_pbox[t][0] = pb;
                s_plab[t] = plab_;
                s_psc[t] = psc;
            }
            bool alive = (psc > 0.3f);
            if (alive && t > 0) {
                float pa = (pb.z - pb.x) * (pb.w - pb.y);
                int kprev = ((t - 1) >> 6) + 1;
                bool sup = false;
                for (int k = 0; k < kprev; ++k) {
                    int p = lane + (k << 6);
                    int pc = (p < t) ? p : 0;
                    float4 qb = *(const float4*)&s_pbox[pc][0];
                    int ga = s_alive[pc];
                    if (p < t && ga) {
                        float lx = fmaxf(pb.x, qb.x), ly = fmaxf(pb.y, qb.y);
                        float rx = fminf(pb.z, qb.z), ry = fminf(pb.w, qb.w);
                        float iw = fmaxf(rx - lx, 0.0f), ih = fmaxf(ry - ly, 0.0f);
                        float inter = iw * ih;
                        float qa = (qb.z - qb.x) * (qb.w - qb.y);
                        float iou = inter / (pa + qa - inter + EPS);
                        sup = sup || (iou > 0.8f);
                    }
                }
                alive = (__ballot(sup) == 0ull);
            }
            if (lane == 0) s_alive[t] = alive ? 1 : 0;
            nconf += alive ? 1 : 0;
            if (nconf >= DETS) { M = t + 1; break; }
            float wax = (pb.z - pb.x) * (pb.w - pb.y);
#pragma unroll
            for (int j = 0; j < SLOTS; ++j) {
                float lx2 = fmaxf(pb.x, x1[j]), ly2 = fmaxf(pb.y, y1[j]);
                float rx2 = fminf(pb.z, x2[j]), ry2 = fminf(pb.w, y2[j]);
                float iw2 = fmaxf(rx2 - lx2, 0.0f), ih2 = fmaxf(ry2 - ly2, 0.0f);
                float inter2 = iw2 * ih2;
                bool hot = (inter2 > 0.0f) && (lb[j] == plab_);
                if (__ballot(hot) != 0ull) {
                    float iou2 = inter2 / (wax + ar[j] - inter2 + EPS);
                    float ie = (lb[j] == plab_) ? iou2 : 0.0f;
                    sc[j] *= expf(-(ie * ie) / 0.5f);
                }
            }
#pragma unroll
            for (int j = 0; j < SLOTS; ++j)
                if (lane + (j << 6) == pick) sc[j] = -1.0f;
            if (lane == (pick >> 6)) aw &= ~(1ull << (pick & 63));
            if (pick == f) {
                int fw = f >> 6;
                unsigned long long w2 = __shfl(aw, fw);
                while (w2 == 0ull && fw < 15) { ++fw; w2 = __shfl(aw, fw); }
                f = (w2 == 0ull) ? TOPK : (fw << 6) + (__ffsll(w2) - 1);
            }
        }
    }

    // ---- emit: alive picks in pick order, then dead padding if needed ----
    float* out_boxes  = out;
    float* out_scores = out + (size_t)B * DETS * 4;
    float* out_labels = out + (size_t)B * DETS * 5;
    int kmax = (M + 63) >> 6;
    int base = 0;
    for (int k = 0; k < kmax; ++k) {
        int p = lane + (k << 6);
        bool av = (p < M) && (s_alive[p] != 0);
        unsigned long long mask = __ballot(av);
        int slot = base + (int)__popcll(mask & ((1ull << lane) - 1ull));
        if (av && slot < DETS) {
            float4 pb = *(const float4*)&s_pbox[p][0];
            float* ob = out_boxes + ((size_t)img * DETS + slot) * 4;
            ob[0] = pb.x; ob[1] = pb.y; ob[2] = pb.z; ob[3] = pb.w;
            out_scores[img * DETS + slot] = s_psc[p];
            out_labels[img * DETS + slot] = (float)s_plab[p];
        }
        base += (int)__popcll(mask);
    }
    if (base < DETS) {
        int dbase = 0;
        for (int k = 0; k < kmax; ++k) {
            int p = lane + (k << 6);
            bool dd = (p < M) && (s_alive[p] == 0);
            unsigned long long mask = __ballot(dd);
            int slot = base + dbase + (int)__popcll(mask & ((1ull << lane) - 1ull));
            if (dd && slot < DETS) {
                float4 pb = *(const float4*)&s_pbox[p][0];
                float* ob = out_boxes + ((size_t)img * DETS + slot) * 4;
                ob[0] = pb.x; ob[1] = pb.y; ob[2] = pb.z; ob[3] = pb.w;
                out_scores[img * DETS + slot] = -1.0f;
                out_labels[img * DETS + slot] = (float)s_plab[p];
            }
            dbase += (int)__popcll(mask);
        }
    }
}

extern "C" void kernel_launch(void* const* d_in, const int* in_sizes, int n_in,
                              void* d_out, int out_size, void* d_ws, size_t ws_size,
                              hipStream_t stream) {
    const float* logits = (const float*)d_in[0];
    const float* rel = (const float*)d_in[1];
    const float* anch = (const float*)d_in[2];
    float* out = (float*)d_out;

    int A = in_sizes[2] / 4;                 // anchors
    int B = in_sizes[0] / (A * NCLS);        // batch

    // workspace layout: [hist | ctr | done] zeroed in ONE memset, then the rest
    char* w = (char*)d_ws;
    unsigned* hist = (unsigned*)w;           w += (size_t)B * NBINS * 4;
    unsigned* ctr = (unsigned*)w;            w += (size_t)B * 4;
    unsigned* done = (unsigned*)w;           w += (size_t)B * 4;
    size_t zbytes = (size_t)(w - (char*)d_ws);
    unsigned long long* cand = (unsigned long long*)w; w += (size_t)B * CANDMAX * 8;
    unsigned* P = (unsigned*)w;              w += (size_t)B * 4;
    w += 4;                                   // keep 8B alignment headroom
    float* scores = (float*)w;
    size_t used = (size_t)(w - (char*)d_ws);
    int use_scores = (used + (size_t)B * A * 4 <= ws_size) ? 1 : 0;

    hipMemsetAsync(d_ws, 0, zbytes, stream);

    dim3 g1(NBLK, (unsigned)B);
    k_score_hist<<<g1, 256, 0, stream>>>(logits, scores, hist, done, P, A, use_scores);
    k_compact<<<g1, 256, 0, stream>>>(logits, use_scores ? scores : nullptr, P, ctr, cand, A);
    k_sortnms<<<B, 1024, 0, stream>>>(cand, ctr, logits, rel, anch, out, A, B);
}

// Round 10
// 272.964 us; speedup vs baseline: 1.1102x; 1.0093x over previous
//
#include <hip/hip_runtime.h>
#include <math.h>

// ---------------- constants from the reference ----------------
#define NCLS 10
#define TOPK 1000
#define DETS 100
#define CANDMAX 4096
#define SLOTS 16   // 16 * 64 lanes = 1024 >= TOPK (full fallback)
#define ACTK 256   // fast-path active set: 4 slots * 64 lanes

// max-logit binning: monotone 2-segment map, 256 bins.
// bin 0 = gated (m <= MGATE, score <= ~0.05). Seg A (MGATE,2.2] -> 1..160,
// seg B (2.2, ~4.5] -> 161..255 (0.024 logit/bin at the selection region).
#define NB2 256
#define MGATE (-2.9444389791664403f)   // ln(0.05/0.95)
#define SEAM 2.2f
#define SCA 30.907200f                  // 159 / (SEAM - MGATE)
#define SCB 41.0f
#define NBLK 64    // blocks per image for the score/compact passes

__device__ __forceinline__ float sigmoidf_(float x) {
    return 1.0f / (1.0f + expf(-x));
}

__device__ __forceinline__ int mbin_(float m) {
    if (!(m > MGATE)) return 0;
    int b;
    if (m > SEAM) { b = 161 + (int)((m - SEAM) * SCB); if (b > 255) b = 255; }
    else          { b = 1 + (int)((m - MGATE) * SCA);  if (b > 160) b = 160; }
    return b;
}

__device__ __forceinline__ float key_score(const unsigned long long* key, int c) {
    return __uint_as_float(~(unsigned)(key[c] >> 32));
}

// order-isomorphic float<->u32 mapping (total order, bijective)
__device__ __forceinline__ unsigned fkey_(float f) {
    unsigned b = __float_as_uint(f);
    return (b & 0x80000000u) ? ~b : (b | 0x80000000u);
}
__device__ __forceinline__ float funkey_(unsigned k) {
    return __uint_as_float((k & 0x80000000u) ? (k & 0x7FFFFFFFu) : ~k);
}

// 64-lane unsigned max via DPP (row_shr 1/2/4/8 + row_bcast15/31), ~ALU latency.
__device__ __forceinline__ unsigned wave_umax_(unsigned x) {
    unsigned t;
    t = (unsigned)__builtin_amdgcn_update_dpp(0, (int)x, 0x111, 0xF, 0xF, false); x = (x > t) ? x : t;
    t = (unsigned)__builtin_amdgcn_update_dpp(0, (int)x, 0x112, 0xF, 0xF, false); x = (x > t) ? x : t;
    t = (unsigned)__builtin_amdgcn_update_dpp(0, (int)x, 0x114, 0xF, 0xF, false); x = (x > t) ? x : t;
    t = (unsigned)__builtin_amdgcn_update_dpp(0, (int)x, 0x118, 0xF, 0xF, false); x = (x > t) ? x : t;
    t = (unsigned)__builtin_amdgcn_update_dpp(0, (int)x, 0x142, 0xF, 0xF, false); x = (x > t) ? x : t;
    t = (unsigned)__builtin_amdgcn_update_dpp(0, (int)x, 0x143, 0xF, 0xF, false); x = (x > t) ? x : t;
    return (unsigned)__builtin_amdgcn_readlane((int)x, 63);
}

// K1: max-logit -> bin (NO expf), uchar bin cache, x4 LDS sub-hists,
// last-block findP. Selection exactness vs score order is guaranteed by the
// P-1 widening in k_compact (bin width x sigmoid slope >> score ULP).
__global__ __launch_bounds__(256) void k_score_bins(const float* __restrict__ logits,
                                                    unsigned char* __restrict__ binc,
                                                    unsigned* hist,
                                                    unsigned* __restrict__ done,
                                                    unsigned* __restrict__ P,
                                                    int A) {
    __shared__ unsigned h[4][NB2];
    __shared__ int s_last;
    int img = blockIdx.y;
    for (int i = threadIdx.x; i < 4 * NB2; i += 256) ((unsigned*)h)[i] = 0;
    __syncthreads();

    const float* base = logits + (size_t)img * A * NCLS;
    unsigned char* bc = binc + (size_t)img * A;
    int rep = threadIdx.x & 3;
    int nquad = A >> 2;
    for (int q = blockIdx.x * 256 + threadIdx.x; q < nquad; q += NBLK * 256) {
        const float4* lp = (const float4*)(base + (size_t)q * 40);
        float f[40];
#pragma unroll
        for (int i = 0; i < 10; ++i) ((float4*)f)[i] = lp[i];
        unsigned ub = 0;
#pragma unroll
        for (int j = 0; j < 4; ++j) {
            float m = f[10 * j];
#pragma unroll
            for (int c = 1; c < 10; ++c) m = fmaxf(m, f[10 * j + c]);
            int b = mbin_(m);
            ub |= ((unsigned)b) << (8 * j);
            if (b) atomicAdd(&h[rep][b], 1u);
        }
        *(unsigned*)(bc + (size_t)q * 4) = ub;
    }
    int tail0 = nquad << 2;
    if (blockIdx.x == 0) {
        for (int a = tail0 + (int)threadIdx.x; a < A; a += 256) {
            const float* lp2 = base + (size_t)a * NCLS;
            float m = lp2[0];
            for (int c = 1; c < 10; ++c) m = fmaxf(m, lp2[c]);
            int b = mbin_(m);
            bc[a] = (unsigned char)b;
            if (b) atomicAdd(&h[rep][b], 1u);
        }
    }
    __syncthreads();
    for (int i = threadIdx.x; i < NB2; i += 256) {
        unsigned c = h[0][i] + h[1][i] + h[2][i] + h[3][i];
        if (c) atomicAdd(&hist[(size_t)img * NB2 + i], c);
    }
    __syncthreads();
    if (threadIdx.x == 0) {
        __threadfence();   // hist atomics ordered before done increment
        unsigned old = atomicAdd(&done[img], 1u);
        s_last = (old == (unsigned)(NBLK - 1)) ? 1 : 0;
    }
    __syncthreads();
    // last finishing block: smallest bin with suffix count >= TOPK
    if (s_last && threadIdx.x < 64) {
        int lane = threadIdx.x;
        unsigned* hh = hist + (size_t)img * NB2;
        unsigned b4[4];
        unsigned s = 0;
#pragma unroll
        for (int j = 0; j < 4; ++j) { b4[j] = atomicAdd(&hh[lane * 4 + j], 0u); s += b4[j]; }
        unsigned suf = s;
#pragma unroll
        for (int d = 1; d < 64; d <<= 1) {
            unsigned o = __shfl_down(suf, d);
            if (lane + d < 64) suf += o;
        }
        unsigned above = __shfl_down(suf, 1);
        if (lane == 63) above = 0;
        if (lane == 0 && suf < (unsigned)TOPK) P[img] = 0u;  // pathological fallback
        if (above < (unsigned)TOPK && suf >= (unsigned)TOPK) {
            unsigned cum = above;
            for (int j = 3; j >= 0; --j) {
                cum += b4[j];
                if (cum >= (unsigned)TOPK) { P[img] = (unsigned)(lane * 4 + j); break; }
            }
        }
    }
}

// K3: compact via uchar bin cache (select bin >= P-1: provably superset of the
// true top-1000); gather logits + exact score only for taken anchors.
__global__ __launch_bounds__(256) void k_compact(const float* __restrict__ logits,
                                                 const unsigned char* __restrict__ binc,
                                                 const unsigned* __restrict__ P,
                                                 unsigned* __restrict__ ctr,
                                                 unsigned long long* __restrict__ cand,
                                                 int A) {
    int img = blockIdx.y;
    unsigned p = P[img];
    unsigned psel = p ? (p - 1u) : 0u;
    int lane = threadIdx.x & 63;
    const float* base = logits + (size_t)img * A * NCLS;
    const unsigned* b4 = (const unsigned*)(binc + (size_t)img * A);
    int nquad = A >> 2;
    for (int q = blockIdx.x * 256 + threadIdx.x; q < nquad; q += NBLK * 256) {
        unsigned ub = b4[q];
#pragma unroll
        for (int j = 0; j < 4; ++j) {
            unsigned bj = (ub >> (8 * j)) & 0xFFu;
            bool take = (psel == 0u) || (bj >= psel);
            unsigned long long mask = __ballot(take);
            if (mask) {
                int cnt = __popcll(mask);
                int leader = __ffsll((unsigned long long)mask) - 1;
                unsigned pos = 0;
                if (lane == leader) pos = atomicAdd(&ctr[img], (unsigned)cnt);
                pos = (unsigned)__shfl((int)pos, leader);
                if (take) {
                    unsigned slot = pos + (unsigned)__popcll(mask & ((1ull << lane) - 1ull));
                    if (slot < CANDMAX) {
                        unsigned a = (unsigned)(q * 4 + j);
                        const float* lp = base + (size_t)a * NCLS;
                        float m = lp[0];
#pragma unroll
                        for (int c = 1; c < 10; ++c) m = fmaxf(m, lp[c]);
                        float sc = sigmoidf_(m);           // == max(sigmoid(l_c)): monotone
                        sc = (sc > 0.05f) ? sc : 0.0f;     // exact old gate for the key
                        unsigned bits = __float_as_uint(sc);
                        cand[(size_t)img * CANDMAX + slot] =
                            ((unsigned long long)bits << 32) | (unsigned)(~a);
                    }
                }
            }
        }
    }
    int tail0 = nquad << 2;
    if (blockIdx.x == 0) {
        for (int a = tail0 + (int)threadIdx.x; a < A; a += 256) {
            unsigned bj = binc[(size_t)img * A + a];
            if ((psel == 0u) || (bj >= psel)) {
                const float* lp = base + (size_t)a * NCLS;
                float m = lp[0];
                for (int c = 1; c < 10; ++c) m = fmaxf(m, lp[c]);
                float sc = sigmoidf_(m);
                sc = (sc > 0.05f) ? sc : 0.0f;
                unsigned bits = __float_as_uint(sc);
                unsigned pos = atomicAdd(&ctr[img], 1u);
                if (pos < CANDMAX)
                    cand[(size_t)img * CANDMAX + pos] =
                        ((unsigned long long)bits << 32) | (unsigned)(~a);
            }
        }
    }
}

// K4+K5 fused: sort -> decode -> soft-NMS with DPP-argmax picks (exact) ->
// inline incremental greedy NMS -> top-100 emit. Winner box/label broadcast
// via readlane from the winning lane's registers (no LDS read on the chain).
__global__ __launch_bounds__(1024) void k_sortnms(const unsigned long long* __restrict__ cand,
                                                  const unsigned* __restrict__ ctr,
                                                  const float* __restrict__ logits,
                                                  const float* __restrict__ rel,
                                                  const float* __restrict__ anch,
                                                  float* __restrict__ out, int A, int B) {
    __shared__ unsigned long long key[CANDMAX];
    __shared__ float s_box[TOPK][4];
    __shared__ int   s_lab[TOPK];
    __shared__ float s_pbox[TOPK][4];
    __shared__ int   s_plab[TOPK];
    __shared__ float s_psc[TOPK];
    __shared__ int   s_alive[TOPK];

    const float CLIPV = 4.135166556742356f;  // log(1000/16)
    const float EPS = 1e-7f;
    const float W_ = 1333.0f, H_ = 800.0f;

    int img = blockIdx.x;
    int tid = threadIdx.x;

    // ---- sort phase (1024 threads) ----
    unsigned n = ctr[img];
    if (n > CANDMAX) n = CANDMAX;
    int L = (n <= 1024) ? 1024 : (n <= 2048) ? 2048 : CANDMAX;
    for (int i = tid; i < L; i += 1024)
        key[i] = (i < (int)n) ? ~cand[(size_t)img * CANDMAX + i] : ~0ull;
    __syncthreads();
    for (int k = 2; k <= L; k <<= 1) {
        for (int j = k >> 1; j > 0; j >>= 1) {
            for (int i = tid; i < L; i += 1024) {
                int l = i ^ j;
                if (l > i) {
                    unsigned long long va = key[i], vb = key[l];
                    bool up = ((i & k) == 0);
                    if (up ? (va > vb) : (va < vb)) { key[i] = vb; key[l] = va; }
                }
            }
            __syncthreads();
        }
    }
    for (int i = L + tid; i < CANDMAX; i += 1024) key[i] = ~0ull;
    __syncthreads();

    // ---- Phase A (1024 threads, 1 candidate each): decode into LDS ----
    if (tid < TOPK) {
        unsigned long long ik = key[tid];
        unsigned ai = (unsigned)ik;
        if (ai >= (unsigned)A) ai = 0;
        const float* lp = logits + ((size_t)img * A + ai) * NCLS;
        float best = sigmoidf_(lp[0]); int lbb = 0;
#pragma unroll
        for (int cc = 1; cc < NCLS; ++cc) {
            float v = sigmoidf_(lp[cc]);
            if (v > best) { best = v; lbb = cc; }
        }
        const float* rp = rel + ((size_t)img * A + ai) * 4;
        const float* ap = anch + (size_t)ai * 4;
        float a0 = ap[0], a1 = ap[1], a2 = ap[2], a3 = ap[3];
        float wa = a2 - a0, ha = a3 - a1;
        float cxa = a0 + 0.5f * wa, cya = a1 + 0.5f * ha;
        float dx = rp[0], dy = rp[1];
        float dw = fminf(rp[2], CLIPV), dh = fminf(rp[3], CLIPV);
        float cx = dx * wa + cxa, cy = dy * ha + cya;
        float w = expf(dw) * wa, h = expf(dh) * ha;
        s_box[tid][0] = fminf(fmaxf(cx - 0.5f * w, 0.0f), W_);
        s_box[tid][1] = fminf(fmaxf(cy - 0.5f * h, 0.0f), H_);
        s_box[tid][2] = fminf(fmaxf(cx + 0.5f * w, 0.0f), W_);
        s_box[tid][3] = fminf(fmaxf(cy + 0.5f * h, 0.0f), H_);
        s_lab[tid] = lbb;
    }
    __syncthreads();
    if (tid >= 64) return;          // wave 0 only from here; no more barriers
    int lane = tid;

    int M = TOPK;
    int need_full = 0;
    float bound = key_score(key, ACTK);   // init score of first EXCLUDED cand

    // ================= FAST ATTEMPT: DPP-argmax, 4 slots =================
    {
        float sc[4], x1[4], y1[4], x2[4], y2[4], ar[4];
        int lb[4];
#pragma unroll
        for (int j = 0; j < 4; ++j) {
            int c = lane + (j << 6);
            float4 bb = *(const float4*)&s_box[c][0];
            x1[j] = bb.x; y1[j] = bb.y; x2[j] = bb.z; y2[j] = bb.w;
            ar[j] = (bb.z - bb.x) * (bb.w - bb.y);
            lb[j] = s_lab[c];
            sc[j] = key_score(key, c);
        }

        int nconf = 0, Mf = -1;

        for (int t = 0; t < ACTK; ++t) {
            // per-lane best (value desc, slot asc => index asc within lane)
            float bv = sc[0]; int bj = 0;
#pragma unroll
            for (int j = 1; j < 4; ++j)
                if (sc[j] > bv) { bv = sc[j]; bj = j; }
            unsigned mk = fkey_(bv);
            unsigned mx = wave_umax_(mk);          // uniform SGPR result
            float pcur = funkey_(mx);

            // active-set guard: excluded (rank>=256) all have score <= bound;
            // equality resolves to the active set (lower sorted rank).
            if (!(pcur >= bound)) { need_full = 1; break; }

            // lowest-index winner: smallest slot j, then smallest lane
            int pick = -1;
#pragma unroll
            for (int jj = 0; jj < 4; ++jj) {
                if (pick < 0) {
                    unsigned long long mj = __ballot(mk == mx && bj == jj);
                    if (mj) pick = (jj << 6) + (__ffsll(mj) - 1);
                }
            }

            // winner box/label broadcast from winning lane's registers
            int jw = pick >> 6, wl = pick & 63;
            float xs = x1[0], ys = y1[0], zs = x2[0], ws = y2[0]; int ls = lb[0];
            if (jw == 1) { xs = x1[1]; ys = y1[1]; zs = x2[1]; ws = y2[1]; ls = lb[1]; }
            if (jw == 2) { xs = x1[2]; ys = y1[2]; zs = x2[2]; ws = y2[2]; ls = lb[2]; }
            if (jw == 3) { xs = x1[3]; ys = y1[3]; zs = x2[3]; ws = y2[3]; ls = lb[3]; }
            float4 pb;
            pb.x = __int_as_float(__builtin_amdgcn_readlane(__float_as_int(xs), wl));
            pb.y = __int_as_float(__builtin_amdgcn_readlane(__float_as_int(ys), wl));
            pb.z = __int_as_float(__builtin_amdgcn_readlane(__float_as_int(zs), wl));
            pb.w = __int_as_float(__builtin_amdgcn_readlane(__float_as_int(ws), wl));
            int plab_ = __builtin_amdgcn_readlane(ls, wl);

            float psc = fmaxf(pcur, 0.0f);
            if (lane == 0) {
                *(float4*)&s_pbox[t][0] = pb;
                s_plab[t] = plab_;
                s_psc[t] = psc;
            }

            // ---- greedy loads issued early (static unroll, clamped addrs) ----
            float4 qb[4]; int ga[4];
#pragma unroll
            for (int k = 0; k < 4; ++k) {
                int p = lane + (k << 6);
                int pc2 = (p < t) ? p : 0;
                qb[k] = *(const float4*)&s_pbox[pc2][0];
                ga[k] = (p < t) ? s_alive[pc2] : 0;
            }

            // ---- decay (ballot-skip: divide+expf only when a lane is hot) ----
            float wax = (pb.z - pb.x) * (pb.w - pb.y);
#pragma unroll
            for (int j = 0; j < 4; ++j) {
                float lx2 = fmaxf(pb.x, x1[j]), ly2 = fmaxf(pb.y, y1[j]);
                float rx2 = fminf(pb.z, x2[j]), ry2 = fminf(pb.w, y2[j]);
                float iw2 = fmaxf(rx2 - lx2, 0.0f), ih2 = fmaxf(ry2 - ly2, 0.0f);
                float inter2 = iw2 * ih2;
                bool hot = (inter2 > 0.0f) && (lb[j] == plab_);
                if (__ballot(hot) != 0ull) {
                    float iou2 = inter2 / (wax + ar[j] - inter2 + EPS);
                    float ie = (lb[j] == plab_) ? iou2 : 0.0f;
                    sc[j] *= expf(-(ie * ie) / 0.5f);
                }
                // skipped slots/lanes: factor would be expf(-0.0f)==1.0f exactly
            }
            // mark picked (after decay, matching the verified ordering)
#pragma unroll
            for (int j = 0; j < 4; ++j)
                if (lane + (j << 6) == pick) sc[j] = -1.0f;

            // ---- greedy compares + ballot (loads landed under decay) ----
            bool sup = false;
#pragma unroll
            for (int k = 0; k < 4; ++k) {
                if (ga[k]) {
                    float lx = fmaxf(pb.x, qb[k].x), ly = fmaxf(pb.y, qb[k].y);
                    float rx = fminf(pb.z, qb[k].z), ry = fminf(pb.w, qb[k].w);
                    float iw = fmaxf(rx - lx, 0.0f), ih = fmaxf(ry - ly, 0.0f);
                    float inter = iw * ih;
                    float qa = (qb[k].z - qb[k].x) * (qb[k].w - qb[k].y);
                    float iou = inter / (wax + qa - inter + EPS);
                    sup = sup || (iou > 0.8f);
                }
            }
            bool alive = (psc > 0.3f) && (__ballot(sup) == 0ull);
            if (lane == 0) s_alive[t] = alive ? 1 : 0;
            nconf += alive ? 1 : 0;
            if (nconf >= DETS) { Mf = t + 1; break; }
        }
        if (!need_full) {
            if (Mf < 0) need_full = 1;   // exhausted 256 picks with <100 dets
            else M = Mf;
        }
    }

    // ================= FULL FALLBACK: verbatim 16-slot loop =================
    if (need_full) {
        float sc[SLOTS], x1[SLOTS], y1[SLOTS], x2[SLOTS], y2[SLOTS], ar[SLOTS];
        int lb[SLOTS];
#pragma unroll
        for (int j = 0; j < SLOTS; ++j) {
            int c = lane + (j << 6);
            if (c < TOPK) {
                float4 bb = *(const float4*)&s_box[c][0];
                x1[j] = bb.x; y1[j] = bb.y; x2[j] = bb.z; y2[j] = bb.w;
                ar[j] = (bb.z - bb.x) * (bb.w - bb.y);
                lb[j] = s_lab[c];
                sc[j] = key_score(key, c);
            } else {
                sc[j] = -2.0f; lb[j] = -1;
                x1[j] = y1[j] = x2[j] = y2[j] = ar[j] = 0.0f;
            }
        }
        unsigned long long aw = 0;
        if (lane < 15) aw = ~0ull;
        else if (lane == 15) aw = (1ull << (TOPK - 15 * 64)) - 1;
        int f = 0, nconf = 0;
        M = TOPK;
        for (int t = 0; t < TOPK; ++t) {
            int fp = (f < TOPK) ? f : 0;
            float4 fb = *(const float4*)&s_box[fp][0];
            int flab = s_lab[fp];
            int fs = f >> 6;
            float v = sc[0];
#pragma unroll
            for (int j = 1; j < SLOTS; ++j) if (fs == j) v = sc[j];
            float cf = __shfl(v, f & 63);
            float lm = sc[0];
#pragma unroll
            for (int j = 1; j < SLOTS; ++j) lm = fmaxf(lm, sc[j]);
            int pick; float pcur; float4 pb; int plab_;
            unsigned long long bb2 = __ballot(lm > cf);
            if (bb2 == 0) {
                pick = f; pcur = cf; pb = fb; plab_ = flab;
            } else {
                float bv = sc[0]; int bi = lane;
#pragma unroll
                for (int j = 1; j < SLOTS; ++j) {
                    int e = lane + (j << 6);
                    if (sc[j] > bv) { bv = sc[j]; bi = e; }
                }
#pragma unroll
                for (int d = 32; d; d >>= 1) {
                    float ov = __shfl_xor(bv, d);
                    int oi = __shfl_xor(bi, d);
                    if (ov > bv || (ov == bv && oi < bi)) { bv = ov; bi = oi; }
                }
                pick = bi; pcur = bv;
                pb = *(const float4*)&s_box[pick][0];
                plab_ = s_lab[pick];
            }
            float psc = fmaxf(pcur, 0.0f);
            if (lane == 0) {
                *(float4*)&s_pbox[t][0] = pb;
                s_plab[t] = plab_;
                s_psc[t] = psc;
            }
            bool alive = (psc > 0.3f);
            if (alive && t > 0) {
                float pa = (pb.z - pb.x) * (pb.w - pb.y);
                int kprev = ((t - 1) >> 6) + 1;
                bool sup = false;
                for (int k = 0; k < kprev; ++k) {
                    int p = lane + (k << 6);
                    int pc = (p < t) ? p : 0;
                    float4 qb = *(const float4*)&s_pbox[pc][0];
                    int ga = s_alive[pc];
                    if (p < t && ga) {
                        float lx = fmaxf(pb.x, qb.x), ly = fmaxf(pb.y, qb.y);
                        float rx = fminf(pb.z, qb.z), ry = fminf(pb.w, qb.w);
                        float iw = fmaxf(rx - lx, 0.0f), ih = fmaxf(ry - ly, 0.0f);
                        float inter = iw * ih;
                        float qa = (qb.z - qb.x) * (qb.w - qb.y);
                        float iou = inter / (pa + qa - inter + EPS);
                        sup = sup || (iou > 0.8f);
                    }
                }
                alive = (__ballot(sup) == 0ull);
            }
            if (lane == 0) s_alive[t] = alive ? 1 : 0;
            nconf += alive ? 1 : 0;
            if (nconf >= DETS) { M = t + 1; break; }
            float wax = (pb.z - pb.x) * (pb.w - pb.y);
#pragma unroll
            for (int j = 0; j < SLOTS; ++j) {
                float lx2 = fmaxf(pb.x, x1[j]), ly2 = fmaxf(pb.y, y1[j]);
                float rx2 = fminf(pb.z, x2[j]), ry2 = fminf(pb.w, y2[j]);
                float iw2 = fmaxf(rx2 - lx2, 0.0f), ih2 = fmaxf(ry2 - ly2, 0.0f);
                float inter2 = iw2 * ih2;
                bool hot = (inter2 > 0.0f) && (lb[j] == plab_);
                if (__ballot(hot) != 0ull) {
                    float iou2 = inter2 / (wax + ar[j] - inter2 + EPS);
                    float ie = (lb[j] == plab_) ? iou2 : 0.0f;
                    sc[j] *= expf(-(ie * ie) / 0.5f);
                }
            }
#pragma unroll
            for (int j = 0; j < SLOTS; ++j)
                if (lane + (j << 6) == pick) sc[j] = -1.0f;
            if (lane == (pick >> 6)) aw &= ~(1ull << (pick & 63));
            if (pick == f) {
                int fw = f >> 6;
                unsigned long long w2 = __shfl(aw, fw);
                while (w2 == 0ull && fw < 15) { ++fw; w2 = __shfl(aw, fw); }
                f = (w2 == 0ull) ? TOPK : (fw << 6) + (__ffsll(w2) - 1);
            }
        }
    }

    // ---- emit: alive picks in pick order, then dead padding if needed ----
    float* out_boxes  = out;
    float* out_scores = out + (size_t)B * DETS * 4;
    float* out_labels = out + (size_t)B * DETS * 5;
    int kmax = (M + 63) >> 6;
    int base = 0;
    for (int k = 0; k < kmax; ++k) {
        int p = lane + (k << 6);
        bool av = (p < M) && (s_alive[p] != 0);
        unsigned long long mask = __ballot(av);
        int slot = base + (int)__popcll(mask & ((1ull << lane) - 1ull));
        if (av && slot < DETS) {
            float4 pb = *(const float4*)&s_pbox[p][0];
            float* ob = out_boxes + ((size_t)img * DETS + slot) * 4;
            ob[0] = pb.x; ob[1] = pb.y; ob[2] = pb.z; ob[3] = pb.w;
            out_scores[img * DETS + slot] = s_psc[p];
            out_labels[img * DETS + slot] = (float)s_plab[p];
        }
        base += (int)__popcll(mask);
    }
    if (base < DETS) {
        int dbase = 0;
        for (int k = 0; k < kmax; ++k) {
            int p = lane + (k << 6);
            bool dd = (p < M) && (s_alive[p] == 0);
            unsigned long long mask = __ballot(dd);
            int slot = base + dbase + (int)__popcll(mask & ((1ull << lane) - 1ull));
            if (dd && slot < DETS) {
                float4 pb = *(const float4*)&s_pbox[p][0];
                float* ob = out_boxes + ((size_t)img * DETS + slot) * 4;
                ob[0] = pb.x; ob[1] = pb.y; ob[2] = pb.z; ob[3] = pb.w;
                out_scores[img * DETS + slot] = -1.0f;
                out_labels[img * DETS + slot] = (float)s_plab[p];
            }
            dbase += (int)__popcll(mask);
        }
    }
}

extern "C" void kernel_launch(void* const* d_in, const int* in_sizes, int n_in,
                              void* d_out, int out_size, void* d_ws, size_t ws_size,
                              hipStream_t stream) {
    const float* logits = (const float*)d_in[0];
    const float* rel = (const float*)d_in[1];
    const float* anch = (const float*)d_in[2];
    float* out = (float*)d_out;

    int A = in_sizes[2] / 4;                 // anchors
    int B = in_sizes[0] / (A * NCLS);        // batch

    // workspace: [hist | ctr | done] zeroed in ONE memset; then cand, P, bins.
    // Total ~= 8KB + 256KB + 1.6MB ~= 1.9MB (fits the known >=2.33MB floor).
    char* w = (char*)d_ws;
    unsigned* hist = (unsigned*)w;           w += (size_t)B * NB2 * 4;
    unsigned* ctr = (unsigned*)w;            w += (size_t)B * 4;
    unsigned* done = (unsigned*)w;           w += (size_t)B * 4;
    size_t zbytes = (size_t)(w - (char*)d_ws);
    unsigned long long* cand = (unsigned long long*)w; w += (size_t)B * CANDMAX * 8;
    unsigned* P = (unsigned*)w;              w += (size_t)B * 4;
    unsigned char* binc = (unsigned char*)w;

    hipMemsetAsync(d_ws, 0, zbytes, stream);

    dim3 g1(NBLK, (unsigned)B);
    k_score_bins<<<g1, 256, 0, stream>>>(logits, binc, hist, done, P, A);
    k_compact<<<g1, 256, 0, stream>>>(logits, binc, P, ctr, cand, A);
    k_sortnms<<<B, 1024, 0, stream>>>(cand, ctr, logits, rel, anch, out, A, B);
}

// Round 11
// 258.091 us; speedup vs baseline: 1.1742x; 1.0576x over previous
//
#include <hip/hip_runtime.h>
#include <math.h>

// ---------------- constants from the reference ----------------
#define NCLS 10
#define TOPK 1000
#define DETS 100
#define CANDMAX 4096
#define SLOTS 16   // 16 * 64 lanes = 1024 >= TOPK (full fallback)
#define ACTK 256   // fast-path active set: 4 slots * 64 lanes
#define TILE 256   // anchors staged per block-iteration in k_score_bins

// max-logit binning: monotone 2-segment map, 256 bins.
// bin 0 = gated (m <= MGATE, score <= ~0.05). Seg A (MGATE,2.2] -> 1..160,
// seg B (2.2, ~4.5] -> 161..255 (0.024 logit/bin at the selection region).
#define NB2 256
#define MGATE (-2.9444389791664403f)   // ln(0.05/0.95)
#define SEAM 2.2f
#define SCA 30.907200f                  // 159 / (SEAM - MGATE)
#define SCB 41.0f
#define NBLK 64    // blocks per image for the score/compact passes

__device__ __forceinline__ float sigmoidf_(float x) {
    return 1.0f / (1.0f + expf(-x));
}

__device__ __forceinline__ int mbin_(float m) {
    if (!(m > MGATE)) return 0;
    int b;
    if (m > SEAM) { b = 161 + (int)((m - SEAM) * SCB); if (b > 255) b = 255; }
    else          { b = 1 + (int)((m - MGATE) * SCA);  if (b > 160) b = 160; }
    return b;
}

__device__ __forceinline__ float key_score(const unsigned long long* key, int c) {
    return __uint_as_float(~(unsigned)(key[c] >> 32));
}

// order-isomorphic float<->u32 mapping (total order, bijective)
__device__ __forceinline__ unsigned fkey_(float f) {
    unsigned b = __float_as_uint(f);
    return (b & 0x80000000u) ? ~b : (b | 0x80000000u);
}
__device__ __forceinline__ float funkey_(unsigned k) {
    return __uint_as_float((k & 0x80000000u) ? (k & 0x7FFFFFFFu) : ~k);
}

// 64-lane unsigned max via DPP (row_shr 1/2/4/8 + row_bcast15/31), ~ALU latency.
__device__ __forceinline__ unsigned wave_umax_(unsigned x) {
    unsigned t;
    t = (unsigned)__builtin_amdgcn_update_dpp(0, (int)x, 0x111, 0xF, 0xF, false); x = (x > t) ? x : t;
    t = (unsigned)__builtin_amdgcn_update_dpp(0, (int)x, 0x112, 0xF, 0xF, false); x = (x > t) ? x : t;
    t = (unsigned)__builtin_amdgcn_update_dpp(0, (int)x, 0x114, 0xF, 0xF, false); x = (x > t) ? x : t;
    t = (unsigned)__builtin_amdgcn_update_dpp(0, (int)x, 0x118, 0xF, 0xF, false); x = (x > t) ? x : t;
    t = (unsigned)__builtin_amdgcn_update_dpp(0, (int)x, 0x142, 0xF, 0xF, false); x = (x > t) ? x : t;
    t = (unsigned)__builtin_amdgcn_update_dpp(0, (int)x, 0x143, 0xF, 0xF, false); x = (x > t) ? x : t;
    return (unsigned)__builtin_amdgcn_readlane((int)x, 63);
}

// K1: max-logit -> bin (NO expf) with COALESCED loads via LDS-transpose tiles.
// Each block stages 256 anchors (2560 floats, 640 float4, lane-contiguous)
// into LDS, then each thread reduces its own anchor's 10 floats (same values,
// same order as before -> bins bit-identical). uchar bin cache, x4 LDS
// sub-hists, last-block findP.
__global__ __launch_bounds__(256) void k_score_bins(const float* __restrict__ logits,
                                                    unsigned char* __restrict__ binc,
                                                    unsigned* hist,
                                                    unsigned* __restrict__ done,
                                                    unsigned* __restrict__ P,
                                                    int A) {
    __shared__ float tilef[TILE * NCLS];   // 10 KB
    __shared__ unsigned h[4][NB2];         // 4 KB
    __shared__ int s_last;
    int img = blockIdx.y;
    int tid = threadIdx.x;
    for (int i = tid; i < 4 * NB2; i += 256) ((unsigned*)h)[i] = 0;
    __syncthreads();

    const float* base = logits + (size_t)img * A * NCLS;
    unsigned char* bc = binc + (size_t)img * A;
    int rep = tid & 3;

    int ntile = A / TILE;   // full tiles; remainder handled by tail path
    for (int tile = blockIdx.x; tile < ntile; tile += NBLK) {
        const float4* src = (const float4*)(base + (size_t)tile * TILE * NCLS); // 640 f4
        float4 v0 = src[tid];
        float4 v1 = src[256 + tid];
        float4 v2;
        if (tid < 128) v2 = src[512 + tid];
        ((float4*)tilef)[tid] = v0;
        ((float4*)tilef)[256 + tid] = v1;
        if (tid < 128) ((float4*)tilef)[512 + tid] = v2;
        __syncthreads();
        // consume: anchor = tile*256 + tid; its floats at tilef[tid*10 ..)
        float m = tilef[tid * 10];
#pragma unroll
        for (int c = 1; c < 10; ++c) m = fmaxf(m, tilef[tid * 10 + c]);
        int b = mbin_(m);
        bc[(size_t)tile * TILE + tid] = (unsigned char)b;
        if (b) atomicAdd(&h[rep][b], 1u);
        __syncthreads();   // protect tile before next overwrite
    }
    // tail anchors (A % TILE), block x==0 only (tiny, strided ok)
    if (blockIdx.x == 0) {
        for (int a = ntile * TILE + tid; a < A; a += 256) {
            const float* lp2 = base + (size_t)a * NCLS;
            float m = lp2[0];
            for (int c = 1; c < 10; ++c) m = fmaxf(m, lp2[c]);
            int b = mbin_(m);
            bc[a] = (unsigned char)b;
            if (b) atomicAdd(&h[rep][b], 1u);
        }
    }
    __syncthreads();
    for (int i = tid; i < NB2; i += 256) {
        unsigned c = h[0][i] + h[1][i] + h[2][i] + h[3][i];
        if (c) atomicAdd(&hist[(size_t)img * NB2 + i], c);
    }
    __syncthreads();
    if (tid == 0) {
        __threadfence();   // hist atomics ordered before done increment
        unsigned old = atomicAdd(&done[img], 1u);
        s_last = (old == (unsigned)(NBLK - 1)) ? 1 : 0;
    }
    __syncthreads();
    // last finishing block: smallest bin with suffix count >= TOPK
    if (s_last && tid < 64) {
        int lane = tid;
        unsigned* hh = hist + (size_t)img * NB2;
        unsigned b4[4];
        unsigned s = 0;
#pragma unroll
        for (int j = 0; j < 4; ++j) { b4[j] = atomicAdd(&hh[lane * 4 + j], 0u); s += b4[j]; }
        unsigned suf = s;
#pragma unroll
        for (int d = 1; d < 64; d <<= 1) {
            unsigned o = __shfl_down(suf, d);
            if (lane + d < 64) suf += o;
        }
        unsigned above = __shfl_down(suf, 1);
        if (lane == 63) above = 0;
        if (lane == 0 && suf < (unsigned)TOPK) P[img] = 0u;  // pathological fallback
        if (above < (unsigned)TOPK && suf >= (unsigned)TOPK) {
            unsigned cum = above;
            for (int j = 3; j >= 0; --j) {
                cum += b4[j];
                if (cum >= (unsigned)TOPK) { P[img] = (unsigned)(lane * 4 + j); break; }
            }
        }
    }
}

// K3: compact via uchar bin cache (select bin >= P-1: provably superset of the
// true top-1000); gather logits + exact score only for taken anchors.
__global__ __launch_bounds__(256) void k_compact(const float* __restrict__ logits,
                                                 const unsigned char* __restrict__ binc,
                                                 const unsigned* __restrict__ P,
                                                 unsigned* __restrict__ ctr,
                                                 unsigned long long* __restrict__ cand,
                                                 int A) {
    int img = blockIdx.y;
    unsigned p = P[img];
    unsigned psel = p ? (p - 1u) : 0u;
    int lane = threadIdx.x & 63;
    const float* base = logits + (size_t)img * A * NCLS;
    const unsigned* b4 = (const unsigned*)(binc + (size_t)img * A);
    int nquad = A >> 2;
    for (int q = blockIdx.x * 256 + threadIdx.x; q < nquad; q += NBLK * 256) {
        unsigned ub = b4[q];
#pragma unroll
        for (int j = 0; j < 4; ++j) {
            unsigned bj = (ub >> (8 * j)) & 0xFFu;
            bool take = (psel == 0u) || (bj >= psel);
            unsigned long long mask = __ballot(take);
            if (mask) {
                int cnt = __popcll(mask);
                int leader = __ffsll((unsigned long long)mask) - 1;
                unsigned pos = 0;
                if (lane == leader) pos = atomicAdd(&ctr[img], (unsigned)cnt);
                pos = (unsigned)__shfl((int)pos, leader);
                if (take) {
                    unsigned slot = pos + (unsigned)__popcll(mask & ((1ull << lane) - 1ull));
                    if (slot < CANDMAX) {
                        unsigned a = (unsigned)(q * 4 + j);
                        const float* lp = base + (size_t)a * NCLS;
                        float m = lp[0];
#pragma unroll
                        for (int c = 1; c < 10; ++c) m = fmaxf(m, lp[c]);
                        float sc = sigmoidf_(m);           // == max(sigmoid(l_c)): monotone
                        sc = (sc > 0.05f) ? sc : 0.0f;     // exact old gate for the key
                        unsigned bits = __float_as_uint(sc);
                        cand[(size_t)img * CANDMAX + slot] =
                            ((unsigned long long)bits << 32) | (unsigned)(~a);
                    }
                }
            }
        }
    }
    int tail0 = nquad << 2;
    if (blockIdx.x == 0) {
        for (int a = tail0 + (int)threadIdx.x; a < A; a += 256) {
            unsigned bj = binc[(size_t)img * A + a];
            if ((psel == 0u) || (bj >= psel)) {
                const float* lp = base + (size_t)a * NCLS;
                float m = lp[0];
                for (int c = 1; c < 10; ++c) m = fmaxf(m, lp[c]);
                float sc = sigmoidf_(m);
                sc = (sc > 0.05f) ? sc : 0.0f;
                unsigned bits = __float_as_uint(sc);
                unsigned pos = atomicAdd(&ctr[img], 1u);
                if (pos < CANDMAX)
                    cand[(size_t)img * CANDMAX + pos] =
                        ((unsigned long long)bits << 32) | (unsigned)(~a);
            }
        }
    }
}

// K4+K5 fused: sort -> decode -> soft-NMS with DPP-argmax picks (exact) ->
// inline incremental greedy NMS -> top-100 emit. Winner box/label via the
// s_box LDS broadcast read (measured faster than readlane broadcast, R10).
__global__ __launch_bounds__(1024) void k_sortnms(const unsigned long long* __restrict__ cand,
                                                  const unsigned* __restrict__ ctr,
                                                  const float* __restrict__ logits,
                                                  const float* __restrict__ rel,
                                                  const float* __restrict__ anch,
                                                  float* __restrict__ out, int A, int B) {
    __shared__ unsigned long long key[CANDMAX];
    __shared__ float s_box[TOPK][4];
    __shared__ int   s_lab[TOPK];
    __shared__ float s_pbox[TOPK][4];
    __shared__ int   s_plab[TOPK];
    __shared__ float s_psc[TOPK];
    __shared__ int   s_alive[TOPK];

    const float CLIPV = 4.135166556742356f;  // log(1000/16)
    const float EPS = 1e-7f;
    const float W_ = 1333.0f, H_ = 800.0f;

    int img = blockIdx.x;
    int tid = threadIdx.x;

    // ---- sort phase (1024 threads) ----
    unsigned n = ctr[img];
    if (n > CANDMAX) n = CANDMAX;
    int L = (n <= 1024) ? 1024 : (n <= 2048) ? 2048 : CANDMAX;
    for (int i = tid; i < L; i += 1024)
        key[i] = (i < (int)n) ? ~cand[(size_t)img * CANDMAX + i] : ~0ull;
    __syncthreads();
    for (int k = 2; k <= L; k <<= 1) {
        for (int j = k >> 1; j > 0; j >>= 1) {
            for (int i = tid; i < L; i += 1024) {
                int l = i ^ j;
                if (l > i) {
                    unsigned long long va = key[i], vb = key[l];
                    bool up = ((i & k) == 0);
                    if (up ? (va > vb) : (va < vb)) { key[i] = vb; key[l] = va; }
                }
            }
            __syncthreads();
        }
    }
    for (int i = L + tid; i < CANDMAX; i += 1024) key[i] = ~0ull;
    __syncthreads();

    // ---- Phase A (1024 threads, 1 candidate each): decode into LDS ----
    if (tid < TOPK) {
        unsigned long long ik = key[tid];
        unsigned ai = (unsigned)ik;
        if (ai >= (unsigned)A) ai = 0;
        const float* lp = logits + ((size_t)img * A + ai) * NCLS;
        float best = sigmoidf_(lp[0]); int lbb = 0;
#pragma unroll
        for (int cc = 1; cc < NCLS; ++cc) {
            float v = sigmoidf_(lp[cc]);
            if (v > best) { best = v; lbb = cc; }
        }
        const float* rp = rel + ((size_t)img * A + ai) * 4;
        const float* ap = anch + (size_t)ai * 4;
        float a0 = ap[0], a1 = ap[1], a2 = ap[2], a3 = ap[3];
        float wa = a2 - a0, ha = a3 - a1;
        float cxa = a0 + 0.5f * wa, cya = a1 + 0.5f * ha;
        float dx = rp[0], dy = rp[1];
        float dw = fminf(rp[2], CLIPV), dh = fminf(rp[3], CLIPV);
        float cx = dx * wa + cxa, cy = dy * ha + cya;
        float w = expf(dw) * wa, h = expf(dh) * ha;
        s_box[tid][0] = fminf(fmaxf(cx - 0.5f * w, 0.0f), W_);
        s_box[tid][1] = fminf(fmaxf(cy - 0.5f * h, 0.0f), H_);
        s_box[tid][2] = fminf(fmaxf(cx + 0.5f * w, 0.0f), W_);
        s_box[tid][3] = fminf(fmaxf(cy + 0.5f * h, 0.0f), H_);
        s_lab[tid] = lbb;
    }
    __syncthreads();
    if (tid >= 64) return;          // wave 0 only from here; no more barriers
    int lane = tid;

    int M = TOPK;
    int need_full = 0;
    float bound = key_score(key, ACTK);   // init score of first EXCLUDED cand

    // ================= FAST ATTEMPT: DPP-argmax, 4 slots =================
    {
        float sc[4], x1[4], y1[4], x2[4], y2[4], ar[4];
        int lb[4];
#pragma unroll
        for (int j = 0; j < 4; ++j) {
            int c = lane + (j << 6);
            float4 bb = *(const float4*)&s_box[c][0];
            x1[j] = bb.x; y1[j] = bb.y; x2[j] = bb.z; y2[j] = bb.w;
            ar[j] = (bb.z - bb.x) * (bb.w - bb.y);
            lb[j] = s_lab[c];
            sc[j] = key_score(key, c);
        }

        int nconf = 0, Mf = -1;

        for (int t = 0; t < ACTK; ++t) {
            // per-lane best (value desc, slot asc => index asc within lane)
            float bv = sc[0]; int bj = 0;
#pragma unroll
            for (int j = 1; j < 4; ++j)
                if (sc[j] > bv) { bv = sc[j]; bj = j; }
            unsigned mk = fkey_(bv);
            unsigned mx = wave_umax_(mk);          // uniform SGPR result
            float pcur = funkey_(mx);

            // active-set guard: excluded (rank>=256) all have score <= bound;
            // equality resolves to the active set (lower sorted rank).
            if (!(pcur >= bound)) { need_full = 1; break; }

            // lowest-index winner: smallest slot j, then smallest lane
            int pick = -1;
#pragma unroll
            for (int jj = 0; jj < 4; ++jj) {
                if (pick < 0) {
                    unsigned long long mj = __ballot(mk == mx && bj == jj);
                    if (mj) pick = (jj << 6) + (__ffsll(mj) - 1);
                }
            }

            float psc = fmaxf(pcur, 0.0f);
            float4 pb = *(const float4*)&s_box[pick][0];
            int plab_ = s_lab[pick];
            if (lane == 0) {
                *(float4*)&s_pbox[t][0] = pb;
                s_plab[t] = plab_;
                s_psc[t] = psc;
            }

            // ---- greedy loads issued early (static unroll, clamped addrs) ----
            float4 qb[4]; int ga[4];
#pragma unroll
            for (int k = 0; k < 4; ++k) {
                int p = lane + (k << 6);
                int pc2 = (p < t) ? p : 0;
                qb[k] = *(const float4*)&s_pbox[pc2][0];
                ga[k] = (p < t) ? s_alive[pc2] : 0;
            }

            // ---- decay (ballot-skip: divide+expf only when a lane is hot) ----
            float wax = (pb.z - pb.x) * (pb.w - pb.y);
#pragma unroll
            for (int j = 0; j < 4; ++j) {
                float lx2 = fmaxf(pb.x, x1[j]), ly2 = fmaxf(pb.y, y1[j]);
                float rx2 = fminf(pb.z, x2[j]), ry2 = fminf(pb.w, y2[j]);
                float iw2 = fmaxf(rx2 - lx2, 0.0f), ih2 = fmaxf(ry2 - ly2, 0.0f);
                float inter2 = iw2 * ih2;
                bool hot = (inter2 > 0.0f) && (lb[j] == plab_);
                if (__ballot(hot) != 0ull) {
                    float iou2 = inter2 / (wax + ar[j] - inter2 + EPS);
                    float ie = (lb[j] == plab_) ? iou2 : 0.0f;
                    sc[j] *= expf(-(ie * ie) / 0.5f);
                }
                // skipped slots/lanes: factor would be expf(-0.0f)==1.0f exactly
            }
            // mark picked (after decay, matching the verified ordering)
#pragma unroll
            for (int j = 0; j < 4; ++j)
                if (lane + (j << 6) == pick) sc[j] = -1.0f;

            // ---- greedy compares + ballot (loads landed under decay) ----
            bool sup = false;
#pragma unroll
            for (int k = 0; k < 4; ++k) {
                if (ga[k]) {
                    float lx = fmaxf(pb.x, qb[k].x), ly = fmaxf(pb.y, qb[k].y);
                    float rx = fminf(pb.z, qb[k].z), ry = fminf(pb.w, qb[k].w);
                    float iw = fmaxf(rx - lx, 0.0f), ih = fmaxf(ry - ly, 0.0f);
                    float inter = iw * ih;
                    float qa = (qb[k].z - qb[k].x) * (qb[k].w - qb[k].y);
                    float iou = inter / (wax + qa - inter + EPS);
                    sup = sup || (iou > 0.8f);
                }
            }
            bool alive = (psc > 0.3f) && (__ballot(sup) == 0ull);
            if (lane == 0) s_alive[t] = alive ? 1 : 0;
            nconf += alive ? 1 : 0;
            if (nconf >= DETS) { Mf = t + 1; break; }
        }
        if (!need_full) {
            if (Mf < 0) need_full = 1;   // exhausted 256 picks with <100 dets
            else M = Mf;
        }
    }

    // ================= FULL FALLBACK: verbatim 16-slot loop =================
    if (need_full) {
        float sc[SLOTS], x1[SLOTS], y1[SLOTS], x2[SLOTS], y2[SLOTS], ar[SLOTS];
        int lb[SLOTS];
#pragma unroll
        for (int j = 0; j < SLOTS; ++j) {
            int c = lane + (j << 6);
            if (c < TOPK) {
                float4 bb = *(const float4*)&s_box[c][0];
                x1[j] = bb.x; y1[j] = bb.y; x2[j] = bb.z; y2[j] = bb.w;
                ar[j] = (bb.z - bb.x) * (bb.w - bb.y);
                lb[j] = s_lab[c];
                sc[j] = key_score(key, c);
            } else {
                sc[j] = -2.0f; lb[j] = -1;
                x1[j] = y1[j] = x2[j] = y2[j] = ar[j] = 0.0f;
            }
        }
        unsigned long long aw = 0;
        if (lane < 15) aw = ~0ull;
        else if (lane == 15) aw = (1ull << (TOPK - 15 * 64)) - 1;
        int f = 0, nconf = 0;
        M = TOPK;
        for (int t = 0; t < TOPK; ++t) {
            int fp = (f < TOPK) ? f : 0;
            float4 fb = *(const float4*)&s_box[fp][0];
            int flab = s_lab[fp];
            int fs = f >> 6;
            float v = sc[0];
#pragma unroll
            for (int j = 1; j < SLOTS; ++j) if (fs == j) v = sc[j];
            float cf = __shfl(v, f & 63);
            float lm = sc[0];
#pragma unroll
            for (int j = 1; j < SLOTS; ++j) lm = fmaxf(lm, sc[j]);
            int pick; float pcur; float4 pb; int plab_;
            unsigned long long bb2 = __ballot(lm > cf);
            if (bb2 == 0) {
                pick = f; pcur = cf; pb = fb; plab_ = flab;
            } else {
                float bv = sc[0]; int bi = lane;
#pragma unroll
                for (int j = 1; j < SLOTS; ++j) {
                    int e = lane + (j << 6);
                    if (sc[j] > bv) { bv = sc[j]; bi = e; }
                }
#pragma unroll
                for (int d = 32; d; d >>= 1) {
                    float ov = __shfl_xor(bv, d);
                    int oi = __shfl_xor(bi, d);
                    if (ov > bv || (ov == bv && oi < bi)) { bv = ov; bi = oi; }
                }
                pick = bi; pcur = bv;
                pb = *(const float4*)&s_box[pick][0];
                plab_ = s_lab[pick];
            }
            float psc = fmaxf(pcur, 0.0f);
            if (lane == 0) {
                *(float4*)&s_pbox[t][0] = pb;
                s_plab[t] = plab_;
                s_psc[t] = psc;
            }
            bool alive = (psc > 0.3f);
            if (alive && t > 0) {
                float pa = (pb.z - pb.x) * (pb.w - pb.y);
                int kprev = ((t - 1) >> 6) + 1;
                bool sup = false;
                for (int k = 0; k < kprev; ++k) {
                    int p = lane + (k << 6);
                    int pc = (p < t) ? p : 0;
                    float4 qb = *(const float4*)&s_pbox[pc][0];
                    int ga = s_alive[pc];
                    if (p < t && ga) {
                        float lx = fmaxf(pb.x, qb.x), ly = fmaxf(pb.y, qb.y);
                        float rx = fminf(pb.z, qb.z), ry = fminf(pb.w, qb.w);
                        float iw = fmaxf(rx - lx, 0.0f), ih = fmaxf(ry - ly, 0.0f);
                        float inter = iw * ih;
                        float qa = (qb.z - qb.x) * (qb.w - qb.y);
                        float iou = inter / (pa + qa - inter + EPS);
                        sup = sup || (iou > 0.8f);
                    }
                }
                alive = (__ballot(sup) == 0ull);
            }
            if (lane == 0) s_alive[t] = alive ? 1 : 0;
            nconf += alive ? 1 : 0;
            if (nconf >= DETS) { M = t + 1; break; }
            float wax = (pb.z - pb.x) * (pb.w - pb.y);
#pragma unroll
            for (int j = 0; j < SLOTS; ++j) {
                float lx2 = fmaxf(pb.x, x1[j]), ly2 = fmaxf(pb.y, y1[j]);
                float rx2 = fminf(pb.z, x2[j]), ry2 = fminf(pb.w, y2[j]);
                float iw2 = fmaxf(rx2 - lx2, 0.0f), ih2 = fmaxf(ry2 - ly2, 0.0f);
                float inter2 = iw2 * ih2;
                bool hot = (inter2 > 0.0f) && (lb[j] == plab_);
                if (__ballot(hot) != 0ull) {
                    float iou2 = inter2 / (wax + ar[j] - inter2 + EPS);
                    float ie = (lb[j] == plab_) ? iou2 : 0.0f;
                    sc[j] *= expf(-(ie * ie) / 0.5f);
                }
            }
#pragma unroll
            for (int j = 0; j < SLOTS; ++j)
                if (lane + (j << 6) == pick) sc[j] = -1.0f;
            if (lane == (pick >> 6)) aw &= ~(1ull << (pick & 63));
            if (pick == f) {
                int fw = f >> 6;
                unsigned long long w2 = __shfl(aw, fw);
                while (w2 == 0ull && fw < 15) { ++fw; w2 = __shfl(aw, fw); }
                f = (w2 == 0ull) ? TOPK : (fw << 6) + (__ffsll(w2) - 1);
            }
        }
    }

    // ---- emit: alive picks in pick order, then dead padding if needed ----
    float* out_boxes  = out;
    float* out_scores = out + (size_t)B * DETS * 4;
    float* out_labels = out + (size_t)B * DETS * 5;
    int kmax = (M + 63) >> 6;
    int base = 0;
    for (int k = 0; k < kmax; ++k) {
        int p = lane + (k << 6);
        bool av = (p < M) && (s_alive[p] != 0);
        unsigned long long mask = __ballot(av);
        int slot = base + (int)__popcll(mask & ((1ull << lane) - 1ull));
        if (av && slot < DETS) {
            float4 pb = *(const float4*)&s_pbox[p][0];
            float* ob = out_boxes + ((size_t)img * DETS + slot) * 4;
            ob[0] = pb.x; ob[1] = pb.y; ob[2] = pb.z; ob[3] = pb.w;
            out_scores[img * DETS + slot] = s_psc[p];
            out_labels[img * DETS + slot] = (float)s_plab[p];
        }
        base += (int)__popcll(mask);
    }
    if (base < DETS) {
        int dbase = 0;
        for (int k = 0; k < kmax; ++k) {
            int p = lane + (k << 6);
            bool dd = (p < M) && (s_alive[p] == 0);
            unsigned long long mask = __ballot(dd);
            int slot = base + dbase + (int)__popcll(mask & ((1ull << lane) - 1ull));
            if (dd && slot < DETS) {
                float4 pb = *(const float4*)&s_pbox[p][0];
                float* ob = out_boxes + ((size_t)img * DETS + slot) * 4;
                ob[0] = pb.x; ob[1] = pb.y; ob[2] = pb.z; ob[3] = pb.w;
                out_scores[img * DETS + slot] = -1.0f;
                out_labels[img * DETS + slot] = (float)s_plab[p];
            }
            dbase += (int)__popcll(mask);
        }
    }
}

extern "C" void kernel_launch(void* const* d_in, const int* in_sizes, int n_in,
                              void* d_out, int out_size, void* d_ws, size_t ws_size,
                              hipStream_t stream) {
    const float* logits = (const float*)d_in[0];
    const float* rel = (const float*)d_in[1];
    const float* anch = (const float*)d_in[2];
    float* out = (float*)d_out;

    int A = in_sizes[2] / 4;                 // anchors
    int B = in_sizes[0] / (A * NCLS);        // batch

    // workspace: [hist | ctr | done] zeroed in ONE memset; then cand, P, bins.
    // Total ~= 8KB + 256KB + 1.6MB ~= 1.9MB (fits the known >=2.33MB floor).
    char* w = (char*)d_ws;
    unsigned* hist = (unsigned*)w;           w += (size_t)B * NB2 * 4;
    unsigned* ctr = (unsigned*)w;            w += (size_t)B * 4;
    unsigned* done = (unsigned*)w;           w += (size_t)B * 4;
    size_t zbytes = (size_t)(w - (char*)d_ws);
    unsigned long long* cand = (unsigned long long*)w; w += (size_t)B * CANDMAX * 8;
    unsigned* P = (unsigned*)w;              w += (size_t)B * 4;
    unsigned char* binc = (unsigned char*)w;

    hipMemsetAsync(d_ws, 0, zbytes, stream);

    dim3 g1(NBLK, (unsigned)B);
    k_score_bins<<<g1, 256, 0, stream>>>(logits, binc, hist, done, P, A);
    k_compact<<<g1, 256, 0, stream>>>(logits, binc, P, ctr, cand, A);
    k_sortnms<<<B, 1024, 0, stream>>>(cand, ctr, logits, rel, anch, out, A, B);
}

// Round 12
// 226.857 us; speedup vs baseline: 1.3359x; 1.1377x over previous
//
#include <hip/hip_runtime.h>
#include <math.h>

// ---------------- constants from the reference ----------------
#define NCLS 10
#define TOPK 1000
#define DETS 100
#define CANDMAX 4096
#define SLOTS 16   // 16 * 64 lanes = 1024 >= TOPK (full fallback)
#define ACTK 256   // fast-path active set: 4 slots * 64 lanes
#define TILE 256   // anchors staged per block-iteration in k_score_bins

// max-logit binning: monotone 2-segment map, 256 bins.
// bin 0 = gated (m <= MGATE, score <= ~0.05). Seg A (MGATE,2.2] -> 1..160,
// seg B (2.2, ~4.5] -> 161..255 (0.024 logit/bin at the selection region).
#define NB2 256
#define MGATE (-2.9444389791664403f)   // ln(0.05/0.95)
#define SEAM 2.2f
#define SCA 30.907200f                  // 159 / (SEAM - MGATE)
#define SCB 41.0f
#define NBLKB 256  // blocks per image for the bins pass (TLP: 8 blocks/CU)

__device__ __forceinline__ float sigmoidf_(float x) {
    return 1.0f / (1.0f + expf(-x));
}

__device__ __forceinline__ int mbin_(float m) {
    if (!(m > MGATE)) return 0;
    int b;
    if (m > SEAM) { b = 161 + (int)((m - SEAM) * SCB); if (b > 255) b = 255; }
    else          { b = 1 + (int)((m - MGATE) * SCA);  if (b > 160) b = 160; }
    return b;
}

__device__ __forceinline__ float key_score(const unsigned long long* key, int c) {
    return __uint_as_float(~(unsigned)(key[c] >> 32));
}

// order-isomorphic float<->u32 mapping (total order, bijective)
__device__ __forceinline__ unsigned fkey_(float f) {
    unsigned b = __float_as_uint(f);
    return (b & 0x80000000u) ? ~b : (b | 0x80000000u);
}
__device__ __forceinline__ float funkey_(unsigned k) {
    return __uint_as_float((k & 0x80000000u) ? (k & 0x7FFFFFFFu) : ~k);
}

// 64-lane unsigned max via DPP (row_shr 1/2/4/8 + row_bcast15/31), ~ALU latency.
__device__ __forceinline__ unsigned wave_umax_(unsigned x) {
    unsigned t;
    t = (unsigned)__builtin_amdgcn_update_dpp(0, (int)x, 0x111, 0xF, 0xF, false); x = (x > t) ? x : t;
    t = (unsigned)__builtin_amdgcn_update_dpp(0, (int)x, 0x112, 0xF, 0xF, false); x = (x > t) ? x : t;
    t = (unsigned)__builtin_amdgcn_update_dpp(0, (int)x, 0x114, 0xF, 0xF, false); x = (x > t) ? x : t;
    t = (unsigned)__builtin_amdgcn_update_dpp(0, (int)x, 0x118, 0xF, 0xF, false); x = (x > t) ? x : t;
    t = (unsigned)__builtin_amdgcn_update_dpp(0, (int)x, 0x142, 0xF, 0xF, false); x = (x > t) ? x : t;
    t = (unsigned)__builtin_amdgcn_update_dpp(0, (int)x, 0x143, 0xF, 0xF, false); x = (x > t) ? x : t;
    return (unsigned)__builtin_amdgcn_readlane((int)x, 63);
}

// K1: max-logit -> bin (NO expf), LDS-transpose tile staging, uchar bin cache,
// x4 LDS sub-hists, last-block findP. NBLKB=256 blocks/image for TLP.
__global__ __launch_bounds__(256) void k_score_bins(const float* __restrict__ logits,
                                                    unsigned char* __restrict__ binc,
                                                    unsigned* hist,
                                                    unsigned* __restrict__ done,
                                                    unsigned* __restrict__ P,
                                                    int A) {
    __shared__ float tilef[TILE * NCLS];   // 10 KB
    __shared__ unsigned h[4][NB2];         // 4 KB
    __shared__ int s_last;
    int img = blockIdx.y;
    int tid = threadIdx.x;
    for (int i = tid; i < 4 * NB2; i += 256) ((unsigned*)h)[i] = 0;
    __syncthreads();

    const float* base = logits + (size_t)img * A * NCLS;
    unsigned char* bc = binc + (size_t)img * A;
    int rep = tid & 3;

    int ntile = A / TILE;   // full tiles; remainder handled by tail path
    for (int tile = blockIdx.x; tile < ntile; tile += NBLKB) {
        const float4* src = (const float4*)(base + (size_t)tile * TILE * NCLS); // 640 f4
        float4 v0 = src[tid];
        float4 v1 = src[256 + tid];
        float4 v2;
        if (tid < 128) v2 = src[512 + tid];
        ((float4*)tilef)[tid] = v0;
        ((float4*)tilef)[256 + tid] = v1;
        if (tid < 128) ((float4*)tilef)[512 + tid] = v2;
        __syncthreads();
        float m = tilef[tid * 10];
#pragma unroll
        for (int c = 1; c < 10; ++c) m = fmaxf(m, tilef[tid * 10 + c]);
        int b = mbin_(m);
        bc[(size_t)tile * TILE + tid] = (unsigned char)b;
        if (b) atomicAdd(&h[rep][b], 1u);
        __syncthreads();   // protect tile before next overwrite
    }
    // tail anchors (A % TILE), block x==0 only
    if (blockIdx.x == 0) {
        for (int a = ntile * TILE + tid; a < A; a += 256) {
            const float* lp2 = base + (size_t)a * NCLS;
            float m = lp2[0];
            for (int c = 1; c < 10; ++c) m = fmaxf(m, lp2[c]);
            int b = mbin_(m);
            bc[a] = (unsigned char)b;
            if (b) atomicAdd(&h[rep][b], 1u);
        }
    }
    __syncthreads();
    for (int i = tid; i < NB2; i += 256) {
        unsigned c = h[0][i] + h[1][i] + h[2][i] + h[3][i];
        if (c) atomicAdd(&hist[(size_t)img * NB2 + i], c);
    }
    __syncthreads();
    if (tid == 0) {
        __threadfence();   // hist atomics ordered before done increment
        unsigned old = atomicAdd(&done[img], 1u);
        s_last = (old == (unsigned)(NBLKB - 1)) ? 1 : 0;
    }
    __syncthreads();
    // last finishing block: smallest bin with suffix count >= TOPK
    if (s_last && tid < 64) {
        int lane = tid;
        unsigned* hh = hist + (size_t)img * NB2;
        unsigned b4[4];
        unsigned s = 0;
#pragma unroll
        for (int j = 0; j < 4; ++j) { b4[j] = atomicAdd(&hh[lane * 4 + j], 0u); s += b4[j]; }
        unsigned suf = s;
#pragma unroll
        for (int d = 1; d < 64; d <<= 1) {
            unsigned o = __shfl_down(suf, d);
            if (lane + d < 64) suf += o;
        }
        unsigned above = __shfl_down(suf, 1);
        if (lane == 63) above = 0;
        if (lane == 0 && suf < (unsigned)TOPK) P[img] = 0u;  // pathological fallback
        if (above < (unsigned)TOPK && suf >= (unsigned)TOPK) {
            unsigned cum = above;
            for (int j = 3; j >= 0; --j) {
                cum += b4[j];
                if (cum >= (unsigned)TOPK) { P[img] = (unsigned)(lane * 4 + j); break; }
            }
        }
    }
}

// K2 (fused): bin-scan compaction -> key build -> sort -> decode -> soft-NMS
// (DPP-argmax, exact) -> inline greedy NMS -> top-100 emit. One block/image.
// Compaction criterion (bin >= P-1) and key construction are identical to the
// old k_compact; the sort's total order on (score, index) makes the LDS
// compaction order irrelevant -> final sorted keys bit-identical.
__global__ __launch_bounds__(1024) void k_sortnms(const unsigned char* __restrict__ binc,
                                                  const unsigned* __restrict__ P,
                                                  const float* __restrict__ logits,
                                                  const float* __restrict__ rel,
                                                  const float* __restrict__ anch,
                                                  float* __restrict__ out, int A, int B) {
    __shared__ unsigned long long key[CANDMAX];
    __shared__ float s_box[TOPK][4];
    __shared__ int   s_lab[TOPK];
    __shared__ float s_pbox[TOPK][4];
    __shared__ int   s_plab[TOPK];
    __shared__ float s_psc[TOPK];
    __shared__ int   s_alive[TOPK];
    __shared__ unsigned s_n;

    const float CLIPV = 4.135166556742356f;  // log(1000/16)
    const float EPS = 1e-7f;
    const float W_ = 1333.0f, H_ = 800.0f;

    int img = blockIdx.x;
    int tid = threadIdx.x;
    const float* base = logits + (size_t)img * A * NCLS;

    // ---- compaction phase 1: scan bins, collect candidate anchor indices ----
    if (tid == 0) s_n = 0;
    __syncthreads();
    {
        unsigned p = P[img];
        unsigned psel = p ? (p - 1u) : 0u;
        const unsigned* b4 = (const unsigned*)(binc + (size_t)img * A);
        int nquad = A >> 2;
        int nq4 = nquad >> 2;
        for (int g = tid; g < nq4; g += 1024) {
            uint4 u = ((const uint4*)b4)[g];
            unsigned ws[4] = {u.x, u.y, u.z, u.w};
#pragma unroll
            for (int w2 = 0; w2 < 4; ++w2) {
                unsigned ub = ws[w2];
#pragma unroll
                for (int j = 0; j < 4; ++j) {
                    unsigned bj = (ub >> (8 * j)) & 0xFFu;
                    if ((psel == 0u) || (bj >= psel)) {
                        unsigned pos = atomicAdd(&s_n, 1u);
                        if (pos < CANDMAX)
                            key[pos] = (unsigned long long)(unsigned)((g * 4 + w2) * 4 + j);
                    }
                }
            }
        }
        for (int q = (nq4 << 2) + tid; q < nquad; q += 1024) {
            unsigned ub = b4[q];
#pragma unroll
            for (int j = 0; j < 4; ++j) {
                unsigned bj = (ub >> (8 * j)) & 0xFFu;
                if ((psel == 0u) || (bj >= psel)) {
                    unsigned pos = atomicAdd(&s_n, 1u);
                    if (pos < CANDMAX)
                        key[pos] = (unsigned long long)(unsigned)(q * 4 + j);
                }
            }
        }
        for (int a = (nquad << 2) + tid; a < A; a += 1024) {
            unsigned bj = binc[(size_t)img * A + a];
            if ((psel == 0u) || (bj >= psel)) {
                unsigned pos = atomicAdd(&s_n, 1u);
                if (pos < CANDMAX)
                    key[pos] = (unsigned long long)(unsigned)a;
            }
        }
    }
    __syncthreads();
    unsigned n = s_n;
    if (n > CANDMAX) n = CANDMAX;
    int L = (n <= 1024) ? 1024 : (n <= 2048) ? 2048 : CANDMAX;

    // ---- phase 2: gather logits, build exact keys; pad the rest ----
    for (int t2 = tid; t2 < (int)n; t2 += 1024) {
        unsigned a = (unsigned)key[t2];
        const float* lp = base + (size_t)a * NCLS;
        float m = lp[0];
#pragma unroll
        for (int c = 1; c < 10; ++c) m = fmaxf(m, lp[c]);
        float sc = sigmoidf_(m);           // == max(sigmoid(l_c)): monotone
        sc = (sc > 0.05f) ? sc : 0.0f;     // exact old gate for the key
        unsigned bits = __float_as_uint(sc);
        // old: cand = (bits<<32)|~a; key = ~cand = (~bits<<32)|a
        key[t2] = ((unsigned long long)(~bits) << 32) | a;
    }
    for (int i = (int)n + tid; i < CANDMAX; i += 1024) key[i] = ~0ull;
    __syncthreads();

    // ---- sort phase (ascending => best score first, then lowest index) ----
    for (int k = 2; k <= L; k <<= 1) {
        for (int j = k >> 1; j > 0; j >>= 1) {
            for (int i = tid; i < L; i += 1024) {
                int l = i ^ j;
                if (l > i) {
                    unsigned long long va = key[i], vb = key[l];
                    bool up = ((i & k) == 0);
                    if (up ? (va > vb) : (va < vb)) { key[i] = vb; key[l] = va; }
                }
            }
            __syncthreads();
        }
    }

    // ---- Phase A (1024 threads, 1 candidate each): decode into LDS ----
    if (tid < TOPK) {
        unsigned long long ik = key[tid];
        unsigned ai = (unsigned)ik;
        if (ai >= (unsigned)A) ai = 0;
        const float* lp = base + (size_t)ai * NCLS;
        float best = sigmoidf_(lp[0]); int lbb = 0;
#pragma unroll
        for (int cc = 1; cc < NCLS; ++cc) {
            float v = sigmoidf_(lp[cc]);
            if (v > best) { best = v; lbb = cc; }
        }
        const float* rp = rel + ((size_t)img * A + ai) * 4;
        const float* ap = anch + (size_t)ai * 4;
        float a0 = ap[0], a1 = ap[1], a2 = ap[2], a3 = ap[3];
        float wa = a2 - a0, ha = a3 - a1;
        float cxa = a0 + 0.5f * wa, cya = a1 + 0.5f * ha;
        float dx = rp[0], dy = rp[1];
        float dw = fminf(rp[2], CLIPV), dh = fminf(rp[3], CLIPV);
        float cx = dx * wa + cxa, cy = dy * ha + cya;
        float w = expf(dw) * wa, h = expf(dh) * ha;
        s_box[tid][0] = fminf(fmaxf(cx - 0.5f * w, 0.0f), W_);
        s_box[tid][1] = fminf(fmaxf(cy - 0.5f * h, 0.0f), H_);
        s_box[tid][2] = fminf(fmaxf(cx + 0.5f * w, 0.0f), W_);
        s_box[tid][3] = fminf(fmaxf(cy + 0.5f * h, 0.0f), H_);
        s_lab[tid] = lbb;
    }
    __syncthreads();
    if (tid >= 64) return;          // wave 0 only from here; no more barriers
    int lane = tid;

    int M = TOPK;
    int need_full = 0;
    float bound = key_score(key, ACTK);   // init score of first EXCLUDED cand

    // ================= FAST ATTEMPT: DPP-argmax, 4 slots =================
    {
        float sc[4], x1[4], y1[4], x2[4], y2[4], ar[4];
        int lb[4];
#pragma unroll
        for (int j = 0; j < 4; ++j) {
            int c = lane + (j << 6);
            float4 bb = *(const float4*)&s_box[c][0];
            x1[j] = bb.x; y1[j] = bb.y; x2[j] = bb.z; y2[j] = bb.w;
            ar[j] = (bb.z - bb.x) * (bb.w - bb.y);
            lb[j] = s_lab[c];
            sc[j] = key_score(key, c);
        }

        int nconf = 0, Mf = -1;

        for (int t = 0; t < ACTK; ++t) {
            float bv = sc[0]; int bj = 0;
#pragma unroll
            for (int j = 1; j < 4; ++j)
                if (sc[j] > bv) { bv = sc[j]; bj = j; }
            unsigned mk = fkey_(bv);
            unsigned mx = wave_umax_(mk);          // uniform SGPR result
            float pcur = funkey_(mx);

            if (!(pcur >= bound)) { need_full = 1; break; }

            int pick = -1;
#pragma unroll
            for (int jj = 0; jj < 4; ++jj) {
                if (pick < 0) {
                    unsigned long long mj = __ballot(mk == mx && bj == jj);
                    if (mj) pick = (jj << 6) + (__ffsll(mj) - 1);
                }
            }

            float psc = fmaxf(pcur, 0.0f);
            float4 pb = *(const float4*)&s_box[pick][0];
            int plab_ = s_lab[pick];
            if (lane == 0) {
                *(float4*)&s_pbox[t][0] = pb;
                s_plab[t] = plab_;
                s_psc[t] = psc;
            }

            float4 qb[4]; int ga[4];
#pragma unroll
            for (int k = 0; k < 4; ++k) {
                int p = lane + (k << 6);
                int pc2 = (p < t) ? p : 0;
                qb[k] = *(const float4*)&s_pbox[pc2][0];
                ga[k] = (p < t) ? s_alive[pc2] : 0;
            }

            float wax = (pb.z - pb.x) * (pb.w - pb.y);
#pragma unroll
            for (int j = 0; j < 4; ++j) {
                float lx2 = fmaxf(pb.x, x1[j]), ly2 = fmaxf(pb.y, y1[j]);
                float rx2 = fminf(pb.z, x2[j]), ry2 = fminf(pb.w, y2[j]);
                float iw2 = fmaxf(rx2 - lx2, 0.0f), ih2 = fmaxf(ry2 - ly2, 0.0f);
                float inter2 = iw2 * ih2;
                bool hot = (inter2 > 0.0f) && (lb[j] == plab_);
                if (__ballot(hot) != 0ull) {
                    float iou2 = inter2 / (wax + ar[j] - inter2 + EPS);
                    float ie = (lb[j] == plab_) ? iou2 : 0.0f;
                    sc[j] *= expf(-(ie * ie) / 0.5f);
                }
            }
#pragma unroll
            for (int j = 0; j < 4; ++j)
                if (lane + (j << 6) == pick) sc[j] = -1.0f;

            bool sup = false;
#pragma unroll
            for (int k = 0; k < 4; ++k) {
                if (ga[k]) {
                    float lx = fmaxf(pb.x, qb[k].x), ly = fmaxf(pb.y, qb[k].y);
                    float rx = fminf(pb.z, qb[k].z), ry = fminf(pb.w, qb[k].w);
                    float iw = fmaxf(rx - lx, 0.0f), ih = fmaxf(ry - ly, 0.0f);
                    float inter = iw * ih;
                    float qa = (qb[k].z - qb[k].x) * (qb[k].w - qb[k].y);
                    float iou = inter / (wax + qa - inter + EPS);
                    sup = sup || (iou > 0.8f);
                }
            }
            bool alive = (psc > 0.3f) && (__ballot(sup) == 0ull);
            if (lane == 0) s_alive[t] = alive ? 1 : 0;
            nconf += alive ? 1 : 0;
            if (nconf >= DETS) { Mf = t + 1; break; }
        }
        if (!need_full) {
            if (Mf < 0) need_full = 1;   // exhausted 256 picks with <100 dets
            else M = Mf;
        }
    }

    // ================= FULL FALLBACK: verbatim 16-slot loop =================
    if (need_full) {
        float sc[SLOTS], x1[SLOTS], y1[SLOTS], x2[SLOTS], y2[SLOTS], ar[SLOTS];
        int lb[SLOTS];
#pragma unroll
        for (int j = 0; j < SLOTS; ++j) {
            int c = lane + (j << 6);
            if (c < TOPK) {
                float4 bb = *(const float4*)&s_box[c][0];
                x1[j] = bb.x; y1[j] = bb.y; x2[j] = bb.z; y2[j] = bb.w;
                ar[j] = (bb.z - bb.x) * (bb.w - bb.y);
                lb[j] = s_lab[c];
                sc[j] = key_score(key, c);
            } else {
                sc[j] = -2.0f; lb[j] = -1;
                x1[j] = y1[j] = x2[j] = y2[j] = ar[j] = 0.0f;
            }
        }
        unsigned long long aw = 0;
        if (lane < 15) aw = ~0ull;
        else if (lane == 15) aw = (1ull << (TOPK - 15 * 64)) - 1;
        int f = 0, nconf = 0;
        M = TOPK;
        for (int t = 0; t < TOPK; ++t) {
            int fp = (f < TOPK) ? f : 0;
            float4 fb = *(const float4*)&s_box[fp][0];
            int flab = s_lab[fp];
            int fs = f >> 6;
            float v = sc[0];
#pragma unroll
            for (int j = 1; j < SLOTS; ++j) if (fs == j) v = sc[j];
            float cf = __shfl(v, f & 63);
            float lm = sc[0];
#pragma unroll
            for (int j = 1; j < SLOTS; ++j) lm = fmaxf(lm, sc[j]);
            int pick; float pcur; float4 pb; int plab_;
            unsigned long long bb2 = __ballot(lm > cf);
            if (bb2 == 0) {
                pick = f; pcur = cf; pb = fb; plab_ = flab;
            } else {
                float bv = sc[0]; int bi = lane;
#pragma unroll
                for (int j = 1; j < SLOTS; ++j) {
                    int e = lane + (j << 6);
                    if (sc[j] > bv) { bv = sc[j]; bi = e; }
                }
#pragma unroll
                for (int d = 32; d; d >>= 1) {
                    float ov = __shfl_xor(bv, d);
                    int oi = __shfl_xor(bi, d);
                    if (ov > bv || (ov == bv && oi < bi)) { bv = ov; bi = oi; }
                }
                pick = bi; pcur = bv;
                pb = *(const float4*)&s_box[pick][0];
                plab_ = s_lab[pick];
            }
            float psc = fmaxf(pcur, 0.0f);
            if (lane == 0) {
                *(float4*)&s_pbox[t][0] = pb;
                s_plab[t] = plab_;
                s_psc[t] = psc;
            }
            bool alive = (psc > 0.3f);
            if (alive && t > 0) {
                float pa = (pb.z - pb.x) * (pb.w - pb.y);
                int kprev = ((t - 1) >> 6) + 1;
                bool sup = false;
                for (int k = 0; k < kprev; ++k) {
                    int p = lane + (k << 6);
                    int pc = (p < t) ? p : 0;
                    float4 qb = *(const float4*)&s_pbox[pc][0];
                    int ga = s_alive[pc];
                    if (p < t && ga) {
                        float lx = fmaxf(pb.x, qb.x), ly = fmaxf(pb.y, qb.y);
                        float rx = fminf(pb.z, qb.z), ry = fminf(pb.w, qb.w);
                        float iw = fmaxf(rx - lx, 0.0f), ih = fmaxf(ry - ly, 0.0f);
                        float inter = iw * ih;
                        float qa = (qb.z - qb.x) * (qb.w - qb.y);
                        float iou = inter / (pa + qa - inter + EPS);
                        sup = sup || (iou > 0.8f);
                    }
                }
                alive = (__ballot(sup) == 0ull);
            }
            if (lane == 0) s_alive[t] = alive ? 1 : 0;
            nconf += alive ? 1 : 0;
            if (nconf >= DETS) { M = t + 1; break; }
            float wax = (pb.z - pb.x) * (pb.w - pb.y);
#pragma unroll
            for (int j = 0; j < SLOTS; ++j) {
                float lx2 = fmaxf(pb.x, x1[j]), ly2 = fmaxf(pb.y, y1[j]);
                float rx2 = fminf(pb.z, x2[j]), ry2 = fminf(pb.w, y2[j]);
                float iw2 = fmaxf(rx2 - lx2, 0.0f), ih2 = fmaxf(ry2 - ly2, 0.0f);
                float inter2 = iw2 * ih2;
                bool hot = (inter2 > 0.0f) && (lb[j] == plab_);
                if (__ballot(hot) != 0ull) {
                    float iou2 = inter2 / (wax + ar[j] - inter2 + EPS);
                    float ie = (lb[j] == plab_) ? iou2 : 0.0f;
                    sc[j] *= expf(-(ie * ie) / 0.5f);
                }
            }
#pragma unroll
            for (int j = 0; j < SLOTS; ++j)
                if (lane + (j << 6) == pick) sc[j] = -1.0f;
            if (lane == (pick >> 6)) aw &= ~(1ull << (pick & 63));
            if (pick == f) {
                int fw = f >> 6;
                unsigned long long w2 = __shfl(aw, fw);
                while (w2 == 0ull && fw < 15) { ++fw; w2 = __shfl(aw, fw); }
                f = (w2 == 0ull) ? TOPK : (fw << 6) + (__ffsll(w2) - 1);
            }
        }
    }

    // ---- emit: alive picks in pick order, then dead padding if needed ----
    float* out_boxes  = out;
    float* out_scores = out + (size_t)B * DETS * 4;
    float* out_labels = out + (size_t)B * DETS * 5;
    int kmax = (M + 63) >> 6;
    int base2 = 0;
    for (int k = 0; k < kmax; ++k) {
        int p = lane + (k << 6);
        bool av = (p < M) && (s_alive[p] != 0);
        unsigned long long mask = __ballot(av);
        int slot = base2 + (int)__popcll(mask & ((1ull << lane) - 1ull));
        if (av && slot < DETS) {
            float4 pb = *(const float4*)&s_pbox[p][0];
            float* ob = out_boxes + ((size_t)img * DETS + slot) * 4;
            ob[0] = pb.x; ob[1] = pb.y; ob[2] = pb.z; ob[3] = pb.w;
            out_scores[img * DETS + slot] = s_psc[p];
            out_labels[img * DETS + slot] = (float)s_plab[p];
        }
        base2 += (int)__popcll(mask);
    }
    if (base2 < DETS) {
        int dbase = 0;
        for (int k = 0; k < kmax; ++k) {
            int p = lane + (k << 6);
            bool dd = (p < M) && (s_alive[p] == 0);
            unsigned long long mask = __ballot(dd);
            int slot = base2 + dbase + (int)__popcll(mask & ((1ull << lane) - 1ull));
            if (dd && slot < DETS) {
                float4 pb = *(const float4*)&s_pbox[p][0];
                float* ob = out_boxes + ((size_t)img * DETS + slot) * 4;
                ob[0] = pb.x; ob[1] = pb.y; ob[2] = pb.z; ob[3] = pb.w;
                out_scores[img * DETS + slot] = -1.0f;
                out_labels[img * DETS + slot] = (float)s_plab[p];
            }
            dbase += (int)__popcll(mask);
        }
    }
}

extern "C" void kernel_launch(void* const* d_in, const int* in_sizes, int n_in,
                              void* d_out, int out_size, void* d_ws, size_t ws_size,
                              hipStream_t stream) {
    const float* logits = (const float*)d_in[0];
    const float* rel = (const float*)d_in[1];
    const float* anch = (const float*)d_in[2];
    float* out = (float*)d_out;

    int A = in_sizes[2] / 4;                 // anchors
    int B = in_sizes[0] / (A * NCLS);        // batch

    // workspace: [hist | done] zeroed in ONE memset; then P, bins (~1.6MB).
    char* w = (char*)d_ws;
    unsigned* hist = (unsigned*)w;           w += (size_t)B * NB2 * 4;
    unsigned* done = (unsigned*)w;           w += (size_t)B * 4;
    size_t zbytes = (size_t)(w - (char*)d_ws);
    unsigned* P = (unsigned*)w;              w += (size_t)B * 4;
    unsigned char* binc = (unsigned char*)w;

    hipMemsetAsync(d_ws, 0, zbytes, stream);

    dim3 g1(NBLKB, (unsigned)B);
    k_score_bins<<<g1, 256, 0, stream>>>(logits, binc, hist, done, P, A);
    k_sortnms<<<B, 1024, 0, stream>>>(binc, P, logits, rel, anch, out, A, B);
}